// Round 2
// baseline (891.151 us; speedup 1.0000x reference)
//
#include <hip/hip_runtime.h>
#include <hip/hip_bf16.h>
#include <math.h>

#define AS1 __attribute__((address_space(1)))
#define AS3 __attribute__((address_space(3)))

typedef __attribute__((ext_vector_type(8))) short bf16x8;
typedef __attribute__((ext_vector_type(4))) float f32x4;
typedef __hip_bfloat16 bf16;

namespace {
constexpr int kBatch = 4, kS = 2048, kD = 512;
constexpr int kRows = kBatch * kS;   // 8192
constexpr int kTopK = 64;
}

__device__ __forceinline__ void async16(void* lds, const void* g) {
  // global->LDS direct, 16B/lane; LDS dest is wave-uniform base + lane*16
  __builtin_amdgcn_global_load_lds((AS1 void*)g, (AS3 void*)lds, 16, 0, 0);
}

// ---------- fp32 -> bf16 h/m/l 3-way split (represents x to ~2^-27 rel) ----------
__global__ __launch_bounds__(256) void split3(
    const float* __restrict__ in, bf16* __restrict__ h, bf16* __restrict__ m,
    bf16* __restrict__ l, int n) {
  int i = blockIdx.x * 256 + threadIdx.x;
  const int stride = gridDim.x * 256;
  for (; i < n; i += stride) {
    const float x = in[i];
    const bf16 hh = __float2bfloat16(x);
    const float r = x - __bfloat162float(hh);
    const bf16 mm = __float2bfloat16(r);
    const float r2 = r - __bfloat162float(mm);
    h[i] = hh; m[i] = mm; l[i] = __float2bfloat16(r2);
  }
}

// ---------- C[M,N] = scale*(A @ B^T) + bias, near-fp32 via 6 bf16 products ----------
// A[M,K], B[N,K] row-major as (h,m,l) bf16 triples. Products hh -> acc1;
// hm,mh,hl,lh,mm -> acc2 (magnitude-grouped accumulators minimize rounding).
// Block tile 128x64, BK=32, 4 waves (2x2), wave tile 64x32 (4x2 fragments).
template<int OUTMODE>  // 0: C fp32; 1: (Ch,Cm,Cl) bf16 3-way split output
__global__ __launch_bounds__(256) void gemm6_nt(
    const bf16* __restrict__ Ah, const bf16* __restrict__ Am, const bf16* __restrict__ Al,
    const bf16* __restrict__ Bh, const bf16* __restrict__ Bm, const bf16* __restrict__ Bl,
    float* __restrict__ C, bf16* __restrict__ Ch, bf16* __restrict__ Cm, bf16* __restrict__ Cl,
    const float* __restrict__ bias, float scale, int N, int K,
    long batchA, long batchB, long batchC) {
  // LDS 36 KiB: A h/m/l [128][32] @ el 0,4096,8192 ; B h/m/l [64][32] @ el 12288,14336,16384
  extern __shared__ char smem[];
  bf16* sA = (bf16*)smem;

  const int t = threadIdx.x;
  const int wi = t >> 6;
  const int ln = t & 63;
  const int wr = wi >> 1, wc = wi & 1;
  const int m0 = blockIdx.y * 128, n0 = blockIdx.x * 64;
  const long zA = (long)blockIdx.z * batchA;
  const long zB = (long)blockIdx.z * batchB;
  const long zC = (long)blockIdx.z * batchC;

  // staging: thread t covers 16B chunk (row = t>>2, col8 = t&3); A has 2 row-halves
  const int sr = t >> 2;
  const int sc = (t & 3) << 3;
  const long a0 = zA + (long)(m0 + sr) * K + sc;
  const long a1 = a0 + (long)64 * K;
  const long b0 = zB + (long)(n0 + sr) * K + sc;
  const int lofs = wi * 1024;  // wave-uniform LDS byte base per 4KB chunk

  const int fr = ln & 15;
  const int fk = (ln >> 4) << 3;
  int aoff[4], boff[2];
#pragma unroll
  for (int i = 0; i < 4; ++i) aoff[i] = (wr * 64 + i * 16 + fr) * 32 + fk;
#pragma unroll
  for (int j = 0; j < 2; ++j) boff[j] = (wc * 32 + j * 16 + fr) * 32 + fk;

  f32x4 acc1[4][2] = {}, acc2[4][2] = {};

  for (int kt = 0; kt < K; kt += 32) {
    async16(smem + 0 + lofs, Ah + a0 + kt);
    async16(smem + 4096 + lofs, Ah + a1 + kt);
    async16(smem + 8192 + lofs, Am + a0 + kt);
    async16(smem + 12288 + lofs, Am + a1 + kt);
    async16(smem + 16384 + lofs, Al + a0 + kt);
    async16(smem + 20480 + lofs, Al + a1 + kt);
    async16(smem + 24576 + lofs, Bh + b0 + kt);
    async16(smem + 28672 + lofs, Bm + b0 + kt);
    async16(smem + 32768 + lofs, Bl + b0 + kt);
    __syncthreads();

    bf16x8 AH[4], BH[2], AX[4], BX[2];
#pragma unroll
    for (int i = 0; i < 4; ++i) AH[i] = *(const bf16x8*)(sA + aoff[i]);
#pragma unroll
    for (int j = 0; j < 2; ++j) BH[j] = *(const bf16x8*)(sA + 12288 + boff[j]);
#pragma unroll
    for (int i = 0; i < 4; ++i)
#pragma unroll
      for (int j = 0; j < 2; ++j)
        acc1[i][j] = __builtin_amdgcn_mfma_f32_16x16x32_bf16(AH[i], BH[j], acc1[i][j], 0, 0, 0);
    // l-group: hl + lh
#pragma unroll
    for (int i = 0; i < 4; ++i) AX[i] = *(const bf16x8*)(sA + 8192 + aoff[i]);
#pragma unroll
    for (int j = 0; j < 2; ++j) BX[j] = *(const bf16x8*)(sA + 16384 + boff[j]);
#pragma unroll
    for (int i = 0; i < 4; ++i)
#pragma unroll
      for (int j = 0; j < 2; ++j) {
        acc2[i][j] = __builtin_amdgcn_mfma_f32_16x16x32_bf16(AH[i], BX[j], acc2[i][j], 0, 0, 0);
        acc2[i][j] = __builtin_amdgcn_mfma_f32_16x16x32_bf16(AX[i], BH[j], acc2[i][j], 0, 0, 0);
      }
    // m-group: hm + mh + mm
#pragma unroll
    for (int i = 0; i < 4; ++i) AX[i] = *(const bf16x8*)(sA + 4096 + aoff[i]);
#pragma unroll
    for (int j = 0; j < 2; ++j) BX[j] = *(const bf16x8*)(sA + 14336 + boff[j]);
#pragma unroll
    for (int i = 0; i < 4; ++i)
#pragma unroll
      for (int j = 0; j < 2; ++j) {
        acc2[i][j] = __builtin_amdgcn_mfma_f32_16x16x32_bf16(AH[i], BX[j], acc2[i][j], 0, 0, 0);
        acc2[i][j] = __builtin_amdgcn_mfma_f32_16x16x32_bf16(AX[i], BH[j], acc2[i][j], 0, 0, 0);
        acc2[i][j] = __builtin_amdgcn_mfma_f32_16x16x32_bf16(AX[i], BX[j], acc2[i][j], 0, 0, 0);
      }
    __syncthreads();
  }

  // epilogue: C/D layout col = lane&15, row = (lane>>4)*4 + q
  const int fc = ln & 15;
  const int fr4 = (ln >> 4) << 2;
#pragma unroll
  for (int i = 0; i < 4; ++i) {
    const int rbase = m0 + wr * 64 + i * 16 + fr4;
#pragma unroll
    for (int j = 0; j < 2; ++j) {
      const int c = n0 + wc * 32 + j * 16 + fc;
      const float bv = bias ? bias[c] : 0.0f;
#pragma unroll
      for (int q = 0; q < 4; ++q) {
        const float val = (acc1[i][j][q] + acc2[i][j][q]) * scale + bv;
        const long off = zC + (long)(rbase + q) * N + c;
        if (OUTMODE == 0) {
          C[off] = val;
        } else {
          const bf16 h = __float2bfloat16(val);
          const float r = val - __bfloat162float(h);
          const bf16 m = __float2bfloat16(r);
          Ch[off] = h; Cm[off] = m;
          Cl[off] = __float2bfloat16(r - __bfloat162float(m));
        }
      }
    }
  }
}

// ---------- per-row top-65 select, fp64 boundary refine, softmax, dense attn ----------
__global__ __launch_bounds__(256) void topk_softmax_kernel(
    const float* __restrict__ scores,
    const float* __restrict__ x, const float* __restrict__ Wq, const float* __restrict__ bq,
    const float* __restrict__ Wk, const float* __restrict__ bk,
    float* __restrict__ attn, int* __restrict__ tk_idx, float* __restrict__ tk_p) {
  const int row = blockIdx.x;  // 0..8191
  const int t = threadIdx.x, ln = t & 63, w = t >> 6;
  const float* srow = scores + (long)row * kS;

  __shared__ float lrow[kS];
  __shared__ float s_wv[kTopK + 1];
  __shared__ int s_wc[kTopK + 1];
  __shared__ float s_rv[4];
  __shared__ int s_rc[4];
  __shared__ float s_p[kTopK];
  __shared__ float s_Z;
  __shared__ int s_ref;
  __shared__ float sxq[kD], sx0[kD], sx1[kD];
  __shared__ double rd0[4], rd1[4];

  float v[8];
#pragma unroll
  for (int j = 0; j < 8; ++j) v[j] = srow[t + 256 * j];

  for (int r = 0; r < kTopK + 1; ++r) {
    float bvv = v[0];
    int bj = 0;
#pragma unroll
    for (int j = 1; j < 8; ++j)
      if (v[j] > bvv) { bvv = v[j]; bj = j; }
    int bc = t + 256 * bj;
#pragma unroll
    for (int off = 32; off > 0; off >>= 1) {
      const float ov = __shfl_xor(bvv, off);
      const int oc = __shfl_xor(bc, off);
      if (ov > bvv || (ov == bvv && oc < bc)) { bvv = ov; bc = oc; }
    }
    if (ln == 0) { s_rv[w] = bvv; s_rc[w] = bc; }
    __syncthreads();
    if (t == 0) {
      float fv = s_rv[0];
      int fc = s_rc[0];
      for (int u = 1; u < 4; ++u)
        if (s_rv[u] > fv || (s_rv[u] == fv && s_rc[u] < fc)) { fv = s_rv[u]; fc = s_rc[u]; }
      s_wv[r] = fv;
      s_wc[r] = fc;
    }
    __syncthreads();
    const int fc = s_wc[r];
    if ((fc & 255) == t) v[fc >> 8] = -INFINITY;
  }

  // fp64 boundary refinement: if rank64/rank65 nearly tie, recompute both exactly
  if (t == 0) s_ref = (s_wv[kTopK - 1] - s_wv[kTopK] < 3e-4f) ? 1 : 0;
  __syncthreads();
  if (s_ref) {
    const int b = row >> 11;
    const long xrow = (long)row * kD;
    const int c0 = s_wc[kTopK - 1], c1 = s_wc[kTopK];
    const long k0r = ((long)(b << 11) + c0) * kD;
    const long k1r = ((long)(b << 11) + c1) * kD;
    for (int d = t; d < kD; d += 256) {
      sxq[d] = x[xrow + d];
      sx0[d] = x[k0r + d];
      sx1[d] = x[k1r + d];
    }
    __syncthreads();
    double p0 = 0.0, p1 = 0.0;
    for (int e = t; e < kD; e += 256) {
      double qe = (double)bq[e], k0e = (double)bk[e], k1e = (double)bk[e];
      const float* wq = Wq + (long)e * kD;
      const float* wk = Wk + (long)e * kD;
      for (int d = 0; d < kD; ++d) {
        qe += (double)sxq[d] * (double)wq[d];
        k0e += (double)sx0[d] * (double)wk[d];
        k1e += (double)sx1[d] * (double)wk[d];
      }
      p0 += qe * k0e;
      p1 += qe * k1e;
    }
#pragma unroll
    for (int off = 32; off > 0; off >>= 1) {
      p0 += __shfl_down(p0, off);
      p1 += __shfl_down(p1, off);
    }
    if (ln == 0) { rd0[w] = p0; rd1[w] = p1; }
    __syncthreads();
    if (t == 0) {
      const double d0 = rd0[0] + rd0[1] + rd0[2] + rd0[3];
      const double d1 = rd1[0] + rd1[1] + rd1[2] + rd1[3];
      if (d1 > d0 || (d1 == d0 && c1 < c0)) {
        s_wc[kTopK - 1] = c1;
        s_wv[kTopK - 1] = s_wv[kTopK];
      }
    }
    __syncthreads();
  }

  // softmax over the kept 64 (s_wv[0] is the max)
  if (t < kTopK) s_p[t] = expf(s_wv[t] - s_wv[0]);
  __syncthreads();
  if (t == 0) {
    float Z = 0.f;
    for (int i = 0; i < kTopK; ++i) Z += s_p[i];
    s_Z = Z;
  }
  __syncthreads();
  if (t < kTopK) {
    const float p = s_p[t] / s_Z;
    s_p[t] = p;
    tk_idx[(long)row * kTopK + t] = s_wc[t];
    tk_p[(long)row * kTopK + t] = p;
  }
  // dense attn row: zeros + scatter in LDS, coalesced float4 store
#pragma unroll
  for (int j = 0; j < 8; ++j) lrow[t + 256 * j] = 0.f;
  __syncthreads();
  if (t < kTopK) lrow[s_wc[t]] = s_p[t];
  __syncthreads();
  float4* dst = (float4*)(attn + (long)row * kS);
  const float4* src = (const float4*)lrow;
  for (int i = t; i < kS / 4; i += 256) dst[i] = src[i];
}

// ---------- mid[row,:] = sum_j p_j * V[idx_j,:] (fp32), emit bf16 h/m/l ----------
__global__ __launch_bounds__(256) void av_kernel(
    const float* __restrict__ V, const int* __restrict__ tk_idx,
    const float* __restrict__ tk_p, bf16* __restrict__ oh, bf16* __restrict__ om,
    bf16* __restrict__ ol) {
  const int row = blockIdx.x;
  const int t = threadIdx.x;
  const int b = row >> 11;
  __shared__ int sidx[kTopK];
  __shared__ float sp[kTopK];
  if (t < kTopK) {
    sidx[t] = tk_idx[(long)row * kTopK + t];
    sp[t] = tk_p[(long)row * kTopK + t];
  }
  __syncthreads();
  const float* Vb = V + (long)b * kS * kD;
  float ax = 0.f, ay = 0.f;
  const int c = t * 2;
#pragma unroll 4
  for (int i = 0; i < kTopK; ++i) {
    const float2 vv = *(const float2*)(Vb + (long)sidx[i] * kD + c);
    ax = fmaf(sp[i], vv.x, ax);
    ay = fmaf(sp[i], vv.y, ay);
  }
  unsigned uh, um, ul;
  {
    const bf16 hx = __float2bfloat16(ax);
    const float rx = ax - __bfloat162float(hx);
    const bf16 mx = __float2bfloat16(rx);
    const bf16 lx = __float2bfloat16(rx - __bfloat162float(mx));
    const bf16 hy = __float2bfloat16(ay);
    const float ry = ay - __bfloat162float(hy);
    const bf16 my = __float2bfloat16(ry);
    const bf16 ly = __float2bfloat16(ry - __bfloat162float(my));
    uh = ((unsigned)__builtin_bit_cast(unsigned short, hy) << 16) | __builtin_bit_cast(unsigned short, hx);
    um = ((unsigned)__builtin_bit_cast(unsigned short, my) << 16) | __builtin_bit_cast(unsigned short, mx);
    ul = ((unsigned)__builtin_bit_cast(unsigned short, ly) << 16) | __builtin_bit_cast(unsigned short, lx);
  }
  ((unsigned*)oh)[(long)row * (kD / 2) + t] = uh;
  ((unsigned*)om)[(long)row * (kD / 2) + t] = um;
  ((unsigned*)ol)[(long)row * (kD / 2) + t] = ul;
}

extern "C" void kernel_launch(void* const* d_in, const int* in_sizes, int n_in,
                              void* d_out, int out_size, void* d_ws, size_t ws_size,
                              hipStream_t stream) {
  (void)in_sizes; (void)n_in; (void)out_size; (void)ws_size;
  const float* x = (const float*)d_in[0];
  const float* Wq = (const float*)d_in[1];
  const float* bq = (const float*)d_in[2];
  const float* Wk = (const float*)d_in[3];
  const float* bk = (const float*)d_in[4];
  const float* Wv = (const float*)d_in[5];
  const float* bv = (const float*)d_in[6];
  const float* Wo = (const float*)d_in[7];
  const float* bo = (const float*)d_in[8];

  float* out = (float*)d_out;             // [4,2048,512]
  float* attn = out + (long)kRows * kD;   // [4,2048,2048]

  const size_t SZ_ROWS = (size_t)kRows * kD * 2;  // 8 MB bf16 [8192,512]
  const size_t SZ_W = (size_t)kD * kD * 2;        // 512 KB bf16 [512,512]
  char* ws = (char*)d_ws;

  // region A (67.1 MB): x3 splits first, then scores overwrites (x3 dead by then)
  bf16* xh = (bf16*)(ws + 0);
  bf16* xm = (bf16*)(ws + SZ_ROWS);
  bf16* xl = (bf16*)(ws + 2 * SZ_ROWS);
  float* scores = (float*)(ws + 0);  // 4*2048*2048*4 = 67108864
  size_t off = 67108864;
  // region B (6.3 MB): weight splits, persistent
  auto alloc = [&](size_t bytes) {
    void* p = ws + off;
    off += (bytes + 255) & ~(size_t)255;
    return p;
  };
  bf16* Wqh = (bf16*)alloc(SZ_W); bf16* Wqm = (bf16*)alloc(SZ_W); bf16* Wql = (bf16*)alloc(SZ_W);
  bf16* Wkh = (bf16*)alloc(SZ_W); bf16* Wkm = (bf16*)alloc(SZ_W); bf16* Wkl = (bf16*)alloc(SZ_W);
  bf16* Wvh = (bf16*)alloc(SZ_W); bf16* Wvm = (bf16*)alloc(SZ_W); bf16* Wvl = (bf16*)alloc(SZ_W);
  bf16* Woh = (bf16*)alloc(SZ_W); bf16* Wom = (bf16*)alloc(SZ_W); bf16* Wol = (bf16*)alloc(SZ_W);
  // region C (50.3 MB): Q3,K3; later reused for mid3 (Q3/K3 dead after scores gemm)
  char* regC = (char*)alloc(6 * SZ_ROWS);
  bf16* Qh = (bf16*)(regC);
  bf16* Qm = (bf16*)(regC + SZ_ROWS);
  bf16* Ql = (bf16*)(regC + 2 * SZ_ROWS);
  bf16* Kh = (bf16*)(regC + 3 * SZ_ROWS);
  bf16* Km = (bf16*)(regC + 4 * SZ_ROWS);
  bf16* Kl = (bf16*)(regC + 5 * SZ_ROWS);
  bf16* midh = (bf16*)(regC);
  bf16* midm = (bf16*)(regC + SZ_ROWS);
  bf16* midl = (bf16*)(regC + 2 * SZ_ROWS);
  // region D/E
  float* Vf = (float*)alloc((size_t)kRows * kD * 4);   // 16.8 MB
  int* tk_idx = (int*)alloc((size_t)kRows * kTopK * 4);
  float* tk_p = (float*)alloc((size_t)kRows * kTopK * 4);

  const float inv_sqrt_d = 1.0f / sqrtf((float)kD);

  // 1. 3-way splits
  split3<<<2048, 256, 0, stream>>>(x, xh, xm, xl, kRows * kD);
  split3<<<256, 256, 0, stream>>>(Wq, Wqh, Wqm, Wql, kD * kD);
  split3<<<256, 256, 0, stream>>>(Wk, Wkh, Wkm, Wkl, kD * kD);
  split3<<<256, 256, 0, stream>>>(Wv, Wvh, Wvm, Wvl, kD * kD);
  split3<<<256, 256, 0, stream>>>(Wo, Woh, Wom, Wol, kD * kD);

  const dim3 gProj(kD / 64, kRows / 128, 1);    // (8, 64, 1)
  const dim3 gScore(kS / 64, kS / 128, kBatch); // (32, 16, 4)
  const int LDS = 36864;

  // 2. Q,K projections -> bf16 h/m/l directly (no fp32 round-trip)
  gemm6_nt<1><<<gProj, 256, LDS, stream>>>(xh, xm, xl, Wqh, Wqm, Wql,
      nullptr, Qh, Qm, Ql, bq, 1.0f, kD, kD, 0, 0, 0);
  gemm6_nt<1><<<gProj, 256, LDS, stream>>>(xh, xm, xl, Wkh, Wkm, Wkl,
      nullptr, Kh, Km, Kl, bk, 1.0f, kD, kD, 0, 0, 0);
  // 3. V projection -> fp32
  gemm6_nt<0><<<gProj, 256, LDS, stream>>>(xh, xm, xl, Wvh, Wvm, Wvl,
      Vf, nullptr, nullptr, nullptr, bv, 1.0f, kD, kD, 0, 0, 0);
  // 4. scores = (Q @ K^T) * inv_sqrt_d  (overwrites region A; x3 dead)
  gemm6_nt<0><<<gScore, 256, LDS, stream>>>(Qh, Qm, Ql, Kh, Km, Kl,
      scores, nullptr, nullptr, nullptr, nullptr, inv_sqrt_d, kS, kD,
      (long)kS * kD, (long)kS * kD, (long)kS * kS);
  // 5. top-64 (+fp64 boundary refine) + softmax + dense attn
  topk_softmax_kernel<<<kRows, 256, 0, stream>>>(scores, x, Wq, bq, Wk, bk,
                                                 attn, tk_idx, tk_p);
  // 6. mid = attn @ V (sparse gather) -> bf16 h/m/l (region C; Q3/K3 dead)
  av_kernel<<<kRows, 256, 0, stream>>>(Vf, tk_idx, tk_p, midh, midm, midl);
  // 7. final projection -> d_out
  gemm6_nt<0><<<gProj, 256, LDS, stream>>>(midh, midm, midl, Woh, Wom, Wol,
      out, nullptr, nullptr, nullptr, bo, 1.0f, kD, kD, 0, 0, 0);
}

// Round 3
// 395.422 us; speedup vs baseline: 2.2537x; 2.2537x over previous
//
#include <hip/hip_runtime.h>
#include <hip/hip_bf16.h>
#include <math.h>

#define AS1 __attribute__((address_space(1)))
#define AS3 __attribute__((address_space(3)))

typedef __attribute__((ext_vector_type(8))) short bf16x8;
typedef __attribute__((ext_vector_type(4))) float f32x4;
typedef __hip_bfloat16 bf16;

namespace {
constexpr int kBatch = 4, kS = 2048, kD = 512;
constexpr int kRows = kBatch * kS;   // 8192
constexpr int kTopK = 64;
}

__device__ __forceinline__ void async16(void* lds, const void* g) {
  // global->LDS direct, 16B/lane; LDS dest is wave-uniform base + lane*16
  __builtin_amdgcn_global_load_lds((AS1 void*)g, (AS3 void*)lds, 16, 0, 0);
}

// ---------- fp32 -> bf16 h/m/l 3-way split (represents x to ~2^-27 rel) ----------
__global__ __launch_bounds__(256) void split3(
    const float* __restrict__ in, bf16* __restrict__ h, bf16* __restrict__ m,
    bf16* __restrict__ l, int n) {
  int i = blockIdx.x * 256 + threadIdx.x;
  const int stride = gridDim.x * 256;
  for (; i < n; i += stride) {
    const float x = in[i];
    const bf16 hh = __float2bfloat16(x);
    const float r = x - __bfloat162float(hh);
    const bf16 mm = __float2bfloat16(r);
    const float r2 = r - __bfloat162float(mm);
    h[i] = hh; m[i] = mm; l[i] = __float2bfloat16(r2);
  }
}

// ---------- C[M,N] = scale*(A @ B^T) + bias, near-fp32 via 6 bf16 products ----------
// A[M,K], B[N,K] row-major as (h,m,l) bf16 triples. Products hh -> acc1;
// hm,mh,hl,lh,mm -> acc2 (magnitude-grouped accumulators minimize rounding).
// Block tile 128x64, BK=32, 4 waves (2x2), wave tile 64x32 (4x2 fragments).
template<int OUTMODE>  // 0: C fp32; 1: (Ch,Cm,Cl) bf16 3-way split output
__global__ __launch_bounds__(256) void gemm6_nt(
    const bf16* __restrict__ Ah, const bf16* __restrict__ Am, const bf16* __restrict__ Al,
    const bf16* __restrict__ Bh, const bf16* __restrict__ Bm, const bf16* __restrict__ Bl,
    float* __restrict__ C, bf16* __restrict__ Ch, bf16* __restrict__ Cm, bf16* __restrict__ Cl,
    const float* __restrict__ bias, float scale, int N, int K,
    long batchA, long batchB, long batchC) {
  // LDS 36 KiB: A h/m/l [128][32] @ el 0,4096,8192 ; B h/m/l [64][32] @ el 12288,14336,16384
  extern __shared__ char smem[];
  bf16* sA = (bf16*)smem;

  const int t = threadIdx.x;
  const int wi = t >> 6;
  const int ln = t & 63;
  const int wr = wi >> 1, wc = wi & 1;
  const int m0 = blockIdx.y * 128, n0 = blockIdx.x * 64;
  const long zA = (long)blockIdx.z * batchA;
  const long zB = (long)blockIdx.z * batchB;
  const long zC = (long)blockIdx.z * batchC;

  // staging: thread t covers 16B chunk (row = t>>2, col8 = t&3); A has 2 row-halves
  const int sr = t >> 2;
  const int sc = (t & 3) << 3;
  const long a0 = zA + (long)(m0 + sr) * K + sc;
  const long a1 = a0 + (long)64 * K;
  const long b0 = zB + (long)(n0 + sr) * K + sc;
  const int lofs = wi * 1024;  // wave-uniform LDS byte base per 4KB chunk

  const int fr = ln & 15;
  const int fk = (ln >> 4) << 3;
  int aoff[4], boff[2];
#pragma unroll
  for (int i = 0; i < 4; ++i) aoff[i] = (wr * 64 + i * 16 + fr) * 32 + fk;
#pragma unroll
  for (int j = 0; j < 2; ++j) boff[j] = (wc * 32 + j * 16 + fr) * 32 + fk;

  f32x4 acc1[4][2] = {}, acc2[4][2] = {};

  for (int kt = 0; kt < K; kt += 32) {
    async16(smem + 0 + lofs, Ah + a0 + kt);
    async16(smem + 4096 + lofs, Ah + a1 + kt);
    async16(smem + 8192 + lofs, Am + a0 + kt);
    async16(smem + 12288 + lofs, Am + a1 + kt);
    async16(smem + 16384 + lofs, Al + a0 + kt);
    async16(smem + 20480 + lofs, Al + a1 + kt);
    async16(smem + 24576 + lofs, Bh + b0 + kt);
    async16(smem + 28672 + lofs, Bm + b0 + kt);
    async16(smem + 32768 + lofs, Bl + b0 + kt);
    __syncthreads();

    bf16x8 AH[4], BH[2], AX[4], BX[2];
#pragma unroll
    for (int i = 0; i < 4; ++i) AH[i] = *(const bf16x8*)(sA + aoff[i]);
#pragma unroll
    for (int j = 0; j < 2; ++j) BH[j] = *(const bf16x8*)(sA + 12288 + boff[j]);
#pragma unroll
    for (int i = 0; i < 4; ++i)
#pragma unroll
      for (int j = 0; j < 2; ++j)
        acc1[i][j] = __builtin_amdgcn_mfma_f32_16x16x32_bf16(AH[i], BH[j], acc1[i][j], 0, 0, 0);
    // l-group: hl + lh
#pragma unroll
    for (int i = 0; i < 4; ++i) AX[i] = *(const bf16x8*)(sA + 8192 + aoff[i]);
#pragma unroll
    for (int j = 0; j < 2; ++j) BX[j] = *(const bf16x8*)(sA + 16384 + boff[j]);
#pragma unroll
    for (int i = 0; i < 4; ++i)
#pragma unroll
      for (int j = 0; j < 2; ++j) {
        acc2[i][j] = __builtin_amdgcn_mfma_f32_16x16x32_bf16(AH[i], BX[j], acc2[i][j], 0, 0, 0);
        acc2[i][j] = __builtin_amdgcn_mfma_f32_16x16x32_bf16(AX[i], BH[j], acc2[i][j], 0, 0, 0);
      }
    // m-group: hm + mh + mm
#pragma unroll
    for (int i = 0; i < 4; ++i) AX[i] = *(const bf16x8*)(sA + 4096 + aoff[i]);
#pragma unroll
    for (int j = 0; j < 2; ++j) BX[j] = *(const bf16x8*)(sA + 14336 + boff[j]);
#pragma unroll
    for (int i = 0; i < 4; ++i)
#pragma unroll
      for (int j = 0; j < 2; ++j) {
        acc2[i][j] = __builtin_amdgcn_mfma_f32_16x16x32_bf16(AH[i], BX[j], acc2[i][j], 0, 0, 0);
        acc2[i][j] = __builtin_amdgcn_mfma_f32_16x16x32_bf16(AX[i], BH[j], acc2[i][j], 0, 0, 0);
        acc2[i][j] = __builtin_amdgcn_mfma_f32_16x16x32_bf16(AX[i], BX[j], acc2[i][j], 0, 0, 0);
      }
    __syncthreads();
  }

  // epilogue: C/D layout col = lane&15, row = (lane>>4)*4 + q
  const int fc = ln & 15;
  const int fr4 = (ln >> 4) << 2;
#pragma unroll
  for (int i = 0; i < 4; ++i) {
    const int rbase = m0 + wr * 64 + i * 16 + fr4;
#pragma unroll
    for (int j = 0; j < 2; ++j) {
      const int c = n0 + wc * 32 + j * 16 + fc;
      const float bv = bias ? bias[c] : 0.0f;
#pragma unroll
      for (int q = 0; q < 4; ++q) {
        const float val = (acc1[i][j][q] + acc2[i][j][q]) * scale + bv;
        const long off = zC + (long)(rbase + q) * N + c;
        if (OUTMODE == 0) {
          C[off] = val;
        } else {
          const bf16 h = __float2bfloat16(val);
          const float r = val - __bfloat162float(h);
          const bf16 m = __float2bfloat16(r);
          Ch[off] = h; Cm[off] = m;
          Cl[off] = __float2bfloat16(r - __bfloat162float(m));
        }
      }
    }
  }
}

// ---------- radix-select top-64 + softmax + dense attn row ----------
// Monotonic float->uint key; histogram top-11 bits, refine within cutoff bin
// (bits 20:10, then 9:0). Exact-key ties broken by smallest column index
// (lax.top_k semantics). Winner order is irrelevant downstream (scatter/sum).
__device__ __forceinline__ unsigned f2key(float f) {
  const unsigned u = __float_as_uint(f);
  return (u & 0x80000000u) ? ~u : (u | 0x80000000u);
}

__global__ __launch_bounds__(256) void topk_softmax_kernel(
    const float* __restrict__ scores, float* __restrict__ attn,
    int* __restrict__ tk_idx, float* __restrict__ tk_p) {
  const int row = blockIdx.x;  // 0..8191
  const int t = threadIdx.x, ln = t & 63, w = t >> 6;
  const float* srow = scores + (long)row * kS;

  __shared__ __align__(16) unsigned hist[2048];  // 8 KB; reused as lrow at the end
  __shared__ float s_wval[kTopK];
  __shared__ int s_wcol[kTopK];
  __shared__ unsigned wsum[4];
  __shared__ int s_cut, s_ngt, s_nw, s_ntie;
  __shared__ int s_tie[128];
  __shared__ float s_tieval;

  if (t == 0) { s_nw = 0; s_ntie = 0; }

  // load 8 scores; cols: j<4 -> 4t+j ; j>=4 -> 1024 + 4t + (j-4)
  float val[8]; unsigned key[8];
  {
    const float4 q0 = ((const float4*)srow)[t];
    const float4 q1 = ((const float4*)srow)[t + 256];
    val[0] = q0.x; val[1] = q0.y; val[2] = q0.z; val[3] = q0.w;
    val[4] = q1.x; val[5] = q1.y; val[6] = q1.z; val[7] = q1.w;
  }
#pragma unroll
  for (int j = 0; j < 8; ++j) key[j] = f2key(val[j]);

  unsigned alive = 0xFFu, winner = 0u;
  int rem = kTopK, done = 0;

  for (int level = 0; level < 3; ++level) {
    const int shift = (level == 0) ? 21 : (level == 1) ? 10 : 0;
    const unsigned bmask = (level == 2) ? 0x3FFu : 0x7FFu;
    for (int i = t; i < 2048; i += 256) hist[i] = 0u;
    __syncthreads();
#pragma unroll
    for (int j = 0; j < 8; ++j)
      if (alive & (1u << j)) atomicAdd(&hist[(key[j] >> shift) & bmask], 1u);
    __syncthreads();

    // suffix scan: thread t owns bins [8t, 8t+8)
    unsigned h[8]; unsigned ts = 0u;
#pragma unroll
    for (int b = 0; b < 8; ++b) { h[b] = hist[8 * t + b]; ts += h[b]; }
    unsigned ss = ts;  // inclusive suffix over lanes (lanes >= ln)
#pragma unroll
    for (int off = 1; off < 64; off <<= 1) {
      const unsigned o = __shfl_down(ss, off);
      if (ln + off < 64) ss += o;
    }
    if (ln == 0) wsum[w] = ss;
    __syncthreads();
    unsigned run = ss - ts;  // alive count in bins >= 8(t+1)
    for (int u = w + 1; u < 4; ++u) run += wsum[u];
#pragma unroll
    for (int b = 7; b >= 0; --b) {
      // `run` = alive count in bins strictly above bin 8t+b
      if (run < (unsigned)rem && run + h[b] >= (unsigned)rem) {
        s_cut = 8 * t + b;   // exactly one thread finds the crossing
        s_ngt = (int)run;
      }
      run += h[b];
    }
    __syncthreads();
    const int cut = s_cut;
    const int ngt = s_ngt;
    const int incut = (int)hist[cut];
    rem -= ngt;
#pragma unroll
    for (int j = 0; j < 8; ++j) {
      if (!(alive & (1u << j))) continue;
      const int b = (int)((key[j] >> shift) & bmask);
      if (b > cut) { winner |= 1u << j; alive &= ~(1u << j); }
      else if (b < cut) alive &= ~(1u << j);
    }
    if (incut == rem) {
      winner |= alive; alive = 0u; done = 1;
    } else if (level == 2) {
      // exact-key ties (identical fp32 values): take `rem` smallest columns
#pragma unroll
      for (int j = 0; j < 8; ++j)
        if (alive & (1u << j)) {
          const int pos = atomicAdd(&s_ntie, 1);
          const int col = (j < 4) ? (4 * t + j) : (1024 + 4 * t + j - 4);
          if (pos < 128) s_tie[pos] = col;
          s_tieval = val[j];  // all tied values identical
        }
      __syncthreads();
      if (w == 0) {
        volatile int* vt = s_tie;
        const int n = (s_ntie < 128) ? s_ntie : 128;
        const int take = (rem < n) ? rem : n;
        for (int it = 0; it < take; ++it) {
          int c0 = (ln < n) ? vt[ln] : 0x7FFFFFFF;
          int c1 = (ln + 64 < n) ? vt[ln + 64] : 0x7FFFFFFF;
          int bc, bs;
          if (c1 < c0) { bc = c1; bs = ln + 64; } else { bc = c0; bs = ln; }
#pragma unroll
          for (int off = 32; off; off >>= 1) {
            const int oc = __shfl_xor(bc, off);
            const int os = __shfl_xor(bs, off);
            if (oc < bc) { bc = oc; bs = os; }
          }
          if (ln == 0) {
            vt[bs] = 0x7FFFFFFF;
            const int p = s_nw;
            s_wcol[p] = bc; s_wval[p] = s_tieval;
            s_nw = p + 1;
          }
        }
      }
      alive = 0u;
      done = 1;
    }
    __syncthreads();
    if (done) break;
  }

  // compact register-held winners (order irrelevant)
#pragma unroll
  for (int j = 0; j < 8; ++j)
    if (winner & (1u << j)) {
      const int pos = atomicAdd(&s_nw, 1);
      const int col = (j < 4) ? (4 * t + j) : (1024 + 4 * t + j - 4);
      if (pos < kTopK) { s_wcol[pos] = col; s_wval[pos] = val[j]; }
    }
  __syncthreads();

  // softmax over the 64 winners — wave 0 only, no barriers inside
  if (w == 0) {
    const float v = s_wval[ln];
    float m = v;
#pragma unroll
    for (int off = 32; off; off >>= 1) m = fmaxf(m, __shfl_xor(m, off));
    float p = expf(v - m);
    float Z = p;
#pragma unroll
    for (int off = 32; off; off >>= 1) Z += __shfl_xor(Z, off);
    p /= Z;
    s_wval[ln] = p;
    tk_idx[(long)row * kTopK + ln] = s_wcol[ln];
    tk_p[(long)row * kTopK + ln] = p;
  }
  __syncthreads();

  // dense attn row: zero + scatter in LDS (reuse hist), coalesced float4 store
  float* lrow = (float*)hist;
  ((float4*)lrow)[t] = make_float4(0.f, 0.f, 0.f, 0.f);
  ((float4*)lrow)[t + 256] = make_float4(0.f, 0.f, 0.f, 0.f);
  __syncthreads();
  if (t < kTopK) lrow[s_wcol[t]] = s_wval[t];
  __syncthreads();
  float4* dst = (float4*)(attn + (long)row * kS);
  dst[t] = ((const float4*)lrow)[t];
  dst[t + 256] = ((const float4*)lrow)[t + 256];
}

// ---------- mid[row,:] = sum_j p_j * V[idx_j,:] (fp32), emit bf16 h/m/l ----------
__global__ __launch_bounds__(256) void av_kernel(
    const float* __restrict__ V, const int* __restrict__ tk_idx,
    const float* __restrict__ tk_p, bf16* __restrict__ oh, bf16* __restrict__ om,
    bf16* __restrict__ ol) {
  const int row = blockIdx.x;
  const int t = threadIdx.x;
  const int b = row >> 11;
  __shared__ int sidx[kTopK];
  __shared__ float sp[kTopK];
  if (t < kTopK) {
    sidx[t] = tk_idx[(long)row * kTopK + t];
    sp[t] = tk_p[(long)row * kTopK + t];
  }
  __syncthreads();
  const float* Vb = V + (long)b * kS * kD;
  float ax = 0.f, ay = 0.f;
  const int c = t * 2;
#pragma unroll 4
  for (int i = 0; i < kTopK; ++i) {
    const float2 vv = *(const float2*)(Vb + (long)sidx[i] * kD + c);
    ax = fmaf(sp[i], vv.x, ax);
    ay = fmaf(sp[i], vv.y, ay);
  }
  unsigned uh, um, ul;
  {
    const bf16 hx = __float2bfloat16(ax);
    const float rx = ax - __bfloat162float(hx);
    const bf16 mx = __float2bfloat16(rx);
    const bf16 lx = __float2bfloat16(rx - __bfloat162float(mx));
    const bf16 hy = __float2bfloat16(ay);
    const float ry = ay - __bfloat162float(hy);
    const bf16 my = __float2bfloat16(ry);
    const bf16 ly = __float2bfloat16(ry - __bfloat162float(my));
    uh = ((unsigned)__builtin_bit_cast(unsigned short, hy) << 16) | __builtin_bit_cast(unsigned short, hx);
    um = ((unsigned)__builtin_bit_cast(unsigned short, my) << 16) | __builtin_bit_cast(unsigned short, mx);
    ul = ((unsigned)__builtin_bit_cast(unsigned short, ly) << 16) | __builtin_bit_cast(unsigned short, lx);
  }
  ((unsigned*)oh)[(long)row * (kD / 2) + t] = uh;
  ((unsigned*)om)[(long)row * (kD / 2) + t] = um;
  ((unsigned*)ol)[(long)row * (kD / 2) + t] = ul;
}

extern "C" void kernel_launch(void* const* d_in, const int* in_sizes, int n_in,
                              void* d_out, int out_size, void* d_ws, size_t ws_size,
                              hipStream_t stream) {
  (void)in_sizes; (void)n_in; (void)out_size; (void)ws_size;
  const float* x = (const float*)d_in[0];
  const float* Wq = (const float*)d_in[1];
  const float* bq = (const float*)d_in[2];
  const float* Wk = (const float*)d_in[3];
  const float* bk = (const float*)d_in[4];
  const float* Wv = (const float*)d_in[5];
  const float* bv = (const float*)d_in[6];
  const float* Wo = (const float*)d_in[7];
  const float* bo = (const float*)d_in[8];

  float* out = (float*)d_out;             // [4,2048,512]
  float* attn = out + (long)kRows * kD;   // [4,2048,2048]

  const size_t SZ_ROWS = (size_t)kRows * kD * 2;  // 8 MB bf16 [8192,512]
  const size_t SZ_W = (size_t)kD * kD * 2;        // 512 KB bf16 [512,512]
  char* ws = (char*)d_ws;

  // region A (67.1 MB): x3 splits first, then scores overwrites (x3 dead by then)
  bf16* xh = (bf16*)(ws + 0);
  bf16* xm = (bf16*)(ws + SZ_ROWS);
  bf16* xl = (bf16*)(ws + 2 * SZ_ROWS);
  float* scores = (float*)(ws + 0);  // 4*2048*2048*4 = 67108864
  size_t off = 67108864;
  // region B (6.3 MB): weight splits, persistent
  auto alloc = [&](size_t bytes) {
    void* p = ws + off;
    off += (bytes + 255) & ~(size_t)255;
    return p;
  };
  bf16* Wqh = (bf16*)alloc(SZ_W); bf16* Wqm = (bf16*)alloc(SZ_W); bf16* Wql = (bf16*)alloc(SZ_W);
  bf16* Wkh = (bf16*)alloc(SZ_W); bf16* Wkm = (bf16*)alloc(SZ_W); bf16* Wkl = (bf16*)alloc(SZ_W);
  bf16* Wvh = (bf16*)alloc(SZ_W); bf16* Wvm = (bf16*)alloc(SZ_W); bf16* Wvl = (bf16*)alloc(SZ_W);
  bf16* Woh = (bf16*)alloc(SZ_W); bf16* Wom = (bf16*)alloc(SZ_W); bf16* Wol = (bf16*)alloc(SZ_W);
  // region C (50.3 MB): Q3,K3; later reused for mid3 (Q3/K3 dead after scores gemm)
  char* regC = (char*)alloc(6 * SZ_ROWS);
  bf16* Qh = (bf16*)(regC);
  bf16* Qm = (bf16*)(regC + SZ_ROWS);
  bf16* Ql = (bf16*)(regC + 2 * SZ_ROWS);
  bf16* Kh = (bf16*)(regC + 3 * SZ_ROWS);
  bf16* Km = (bf16*)(regC + 4 * SZ_ROWS);
  bf16* Kl = (bf16*)(regC + 5 * SZ_ROWS);
  bf16* midh = (bf16*)(regC);
  bf16* midm = (bf16*)(regC + SZ_ROWS);
  bf16* midl = (bf16*)(regC + 2 * SZ_ROWS);
  // region D/E
  float* Vf = (float*)alloc((size_t)kRows * kD * 4);   // 16.8 MB
  int* tk_idx = (int*)alloc((size_t)kRows * kTopK * 4);
  float* tk_p = (float*)alloc((size_t)kRows * kTopK * 4);

  const float inv_sqrt_d = 1.0f / sqrtf((float)kD);

  // 1. 3-way splits
  split3<<<2048, 256, 0, stream>>>(x, xh, xm, xl, kRows * kD);
  split3<<<256, 256, 0, stream>>>(Wq, Wqh, Wqm, Wql, kD * kD);
  split3<<<256, 256, 0, stream>>>(Wk, Wkh, Wkm, Wkl, kD * kD);
  split3<<<256, 256, 0, stream>>>(Wv, Wvh, Wvm, Wvl, kD * kD);
  split3<<<256, 256, 0, stream>>>(Wo, Woh, Wom, Wol, kD * kD);

  const dim3 gProj(kD / 64, kRows / 128, 1);    // (8, 64, 1)
  const dim3 gScore(kS / 64, kS / 128, kBatch); // (32, 16, 4)
  const int LDS = 36864;

  // 2. Q,K projections -> bf16 h/m/l directly (no fp32 round-trip)
  gemm6_nt<1><<<gProj, 256, LDS, stream>>>(xh, xm, xl, Wqh, Wqm, Wql,
      nullptr, Qh, Qm, Ql, bq, 1.0f, kD, kD, 0, 0, 0);
  gemm6_nt<1><<<gProj, 256, LDS, stream>>>(xh, xm, xl, Wkh, Wkm, Wkl,
      nullptr, Kh, Km, Kl, bk, 1.0f, kD, kD, 0, 0, 0);
  // 3. V projection -> fp32
  gemm6_nt<0><<<gProj, 256, LDS, stream>>>(xh, xm, xl, Wvh, Wvm, Wvl,
      Vf, nullptr, nullptr, nullptr, bv, 1.0f, kD, kD, 0, 0, 0);
  // 4. scores = (Q @ K^T) * inv_sqrt_d  (overwrites region A; x3 dead)
  gemm6_nt<0><<<gScore, 256, LDS, stream>>>(Qh, Qm, Ql, Kh, Km, Kl,
      scores, nullptr, nullptr, nullptr, nullptr, inv_sqrt_d, kS, kD,
      (long)kS * kD, (long)kS * kD, (long)kS * kS);
  // 5. radix-select top-64 + softmax + dense attn
  topk_softmax_kernel<<<kRows, 256, 0, stream>>>(scores, attn, tk_idx, tk_p);
  // 6. mid = attn @ V (sparse gather) -> bf16 h/m/l (region C; Q3/K3 dead)
  av_kernel<<<kRows, 256, 0, stream>>>(Vf, tk_idx, tk_p, midh, midm, midl);
  // 7. final projection -> d_out
  gemm6_nt<0><<<gProj, 256, LDS, stream>>>(midh, midm, midl, Woh, Wom, Wol,
      out, nullptr, nullptr, nullptr, bo, 1.0f, kD, kD, 0, 0, 0);
}

// Round 4
// 310.598 us; speedup vs baseline: 2.8691x; 1.2731x over previous
//
#include <hip/hip_runtime.h>
#include <hip/hip_bf16.h>
#include <math.h>

#define AS1 __attribute__((address_space(1)))
#define AS3 __attribute__((address_space(3)))

typedef __attribute__((ext_vector_type(8))) short bf16x8;
typedef __attribute__((ext_vector_type(4))) float f32x4;
typedef __hip_bfloat16 bf16;

namespace {
constexpr int kBatch = 4, kS = 2048, kD = 512;
constexpr int kRows = kBatch * kS;   // 8192
constexpr int kTopK = 64;
}

__device__ __forceinline__ void async16(void* lds, const void* g) {
  // global->LDS direct, 16B/lane; LDS dest is wave-uniform base + lane*16
  __builtin_amdgcn_global_load_lds((AS1 void*)g, (AS3 void*)lds, 16, 0, 0);
}

// ---------- fp32 -> bf16 h/m/l 3-way split ----------
__global__ __launch_bounds__(256) void split3(
    const float* __restrict__ in, bf16* __restrict__ h, bf16* __restrict__ m,
    bf16* __restrict__ l, int n) {
  int i = blockIdx.x * 256 + threadIdx.x;
  const int stride = gridDim.x * 256;
  for (; i < n; i += stride) {
    const float x = in[i];
    const bf16 hh = __float2bfloat16(x);
    const float r = x - __bfloat162float(hh);
    const bf16 mm = __float2bfloat16(r);
    const float r2 = r - __bfloat162float(mm);
    h[i] = hh; m[i] = mm; l[i] = __float2bfloat16(r2);
  }
}

// fused 4-weight split (one launch instead of four)
struct WSplitArgs {
  const float* w[4];
  bf16* h[4]; bf16* m[4]; bf16* l[4];
};
__global__ __launch_bounds__(256) void split3x4(WSplitArgs a, int n) {
  const int g = blockIdx.y;
  const float* in = a.w[g];
  bf16* h = a.h[g]; bf16* m = a.m[g]; bf16* l = a.l[g];
  int i = blockIdx.x * 256 + threadIdx.x;
  const int stride = gridDim.x * 256;
  for (; i < n; i += stride) {
    const float x = in[i];
    const bf16 hh = __float2bfloat16(x);
    const float r = x - __bfloat162float(hh);
    const bf16 mm = __float2bfloat16(r);
    const float r2 = r - __bfloat162float(mm);
    h[i] = hh; m[i] = mm; l[i] = __float2bfloat16(r2);
  }
}

// ---------- C[M,N] = scale*(A @ B^T) + bias, high precision via split bf16 ----------
// A[M,K], B[N,K] row-major as (h,m,l) bf16 triples (l unused when NPROD==3).
// NPROD=6: hh->acc1; hm,mh,hl,lh,mm->acc2.  NPROD=3: hh->acc1; hm,mh->acc2.
// 4 waves (2x2); wave tile (BM/2)x(BN/2); BK=32.
// LDS layout per piece: [superrow s = 2 rows][8 chunks of 16B], physical chunk
// = c2 ^ (s&7) where c2 = (row&1)*4 + kchunk. Staging pre-swizzles the GLOBAL
// source per lane (LDS dest stays linear for global_load_lds); ds_read_b128
// then hits every bank exactly 2x per 16-lane phase (conflict-free).
template<int OUTMODE, int NPROD, int BM, int BN>
__global__ __launch_bounds__(256, 2) void gemm_nt(
    const bf16* __restrict__ Ah, const bf16* __restrict__ Am, const bf16* __restrict__ Al,
    const bf16* __restrict__ Bh, const bf16* __restrict__ Bm, const bf16* __restrict__ Bl,
    float* __restrict__ C, bf16* __restrict__ Ch, bf16* __restrict__ Cm, bf16* __restrict__ Cl,
    const float* __restrict__ bias, float scale, int N, int K,
    long batchA, long batchB, long batchC) {
  constexpr int NP = (NPROD == 6) ? 3 : 2;   // pieces per side
  constexpr int FI = BM / 32, FJ = BN / 32;  // fragments per wave
  constexpr int ABYTES = BM * 64;            // bytes per A piece (BM x 32 bf16)
  constexpr int BBYTES = BN * 64;
  extern __shared__ char smem[];

  const int t = threadIdx.x;
  const int wi = t >> 6, ln = t & 63;
  const int wr = wi >> 1, wc = wi & 1;
  const int m0 = blockIdx.y * BM, n0 = blockIdx.x * BN;
  const long zA = (long)blockIdx.z * batchA;
  const long zB = (long)blockIdx.z * batchB;
  const long zC = (long)blockIdx.z * batchC;

  // ---- staging coords (pre-swizzled global source) ----
  const int ssr = t >> 3;                 // superrow within a 4KB call-span
  const int spc = t & 7;                  // physical chunk this lane fills
  const int slc = spc ^ (ssr & 7);        // logical chunk to fetch
  const int grow = 2 * ssr + (slc >> 2);  // tile-local row 0..63
  const int gk = (slc & 3) << 3;          // k element offset 0/8/16/24
  const long gA = zA + (long)(m0 + grow) * K + gk;
  const long gB = zB + (long)(n0 + grow) * K + gk;
  const int lofs = wi * 1024;             // wave-uniform LDS base per call-span

  // ---- fragment read offsets (bytes within a piece) ----
  const int fr = ln & 15, cc = ln >> 4;
  const int c2 = ((fr & 1) << 2) | cc;
  int aoff[FI], boff[FJ];
#pragma unroll
  for (int i = 0; i < FI; ++i) {
    const int s = (wr * (BM / 2) + i * 16 + fr) >> 1;
    aoff[i] = s * 128 + ((c2 ^ (s & 7)) << 4);
  }
#pragma unroll
  for (int j = 0; j < FJ; ++j) {
    const int s = (wc * (BN / 2) + j * 16 + fr) >> 1;
    boff[j] = s * 128 + ((c2 ^ (s & 7)) << 4);
  }

  f32x4 acc1[FI][FJ] = {}, acc2[FI][FJ] = {};

  for (int kt = 0; kt < K; kt += 32) {
#pragma unroll
    for (int q = 0; q < BM / 64; ++q) {
      const long ga = gA + (long)(q * 64) * K + kt;
      async16(smem + 0 * ABYTES + q * 4096 + lofs, Ah + ga);
      async16(smem + 1 * ABYTES + q * 4096 + lofs, Am + ga);
      if (NPROD == 6) async16(smem + 2 * ABYTES + q * 4096 + lofs, Al + ga);
    }
#pragma unroll
    for (int q = 0; q < BN / 64; ++q) {
      const long gb = gB + (long)(q * 64) * K + kt;
      async16(smem + NP * ABYTES + 0 * BBYTES + q * 4096 + lofs, Bh + gb);
      async16(smem + NP * ABYTES + 1 * BBYTES + q * 4096 + lofs, Bm + gb);
      if (NPROD == 6) async16(smem + NP * ABYTES + 2 * BBYTES + q * 4096 + lofs, Bl + gb);
    }
    __syncthreads();  // drains vmcnt (global_load_lds)

    bf16x8 AH[FI], BH[FJ], AX[FI], BX[FJ];
#pragma unroll
    for (int i = 0; i < FI; ++i) AH[i] = *(const bf16x8*)(smem + aoff[i]);
#pragma unroll
    for (int j = 0; j < FJ; ++j) BH[j] = *(const bf16x8*)(smem + NP * ABYTES + boff[j]);
#pragma unroll
    for (int i = 0; i < FI; ++i)
#pragma unroll
      for (int j = 0; j < FJ; ++j)
        acc1[i][j] = __builtin_amdgcn_mfma_f32_16x16x32_bf16(AH[i], BH[j], acc1[i][j], 0, 0, 0);
    if (NPROD == 6) {  // l-group: hl + lh
#pragma unroll
      for (int i = 0; i < FI; ++i) AX[i] = *(const bf16x8*)(smem + 2 * ABYTES + aoff[i]);
#pragma unroll
      for (int j = 0; j < FJ; ++j) BX[j] = *(const bf16x8*)(smem + NP * ABYTES + 2 * BBYTES + boff[j]);
#pragma unroll
      for (int i = 0; i < FI; ++i)
#pragma unroll
        for (int j = 0; j < FJ; ++j) {
          acc2[i][j] = __builtin_amdgcn_mfma_f32_16x16x32_bf16(AH[i], BX[j], acc2[i][j], 0, 0, 0);
          acc2[i][j] = __builtin_amdgcn_mfma_f32_16x16x32_bf16(AX[i], BH[j], acc2[i][j], 0, 0, 0);
        }
    }
    // m-group: hm + mh (+ mm when NPROD==6)
#pragma unroll
    for (int i = 0; i < FI; ++i) AX[i] = *(const bf16x8*)(smem + 1 * ABYTES + aoff[i]);
#pragma unroll
    for (int j = 0; j < FJ; ++j) BX[j] = *(const bf16x8*)(smem + NP * ABYTES + 1 * BBYTES + boff[j]);
#pragma unroll
    for (int i = 0; i < FI; ++i)
#pragma unroll
      for (int j = 0; j < FJ; ++j) {
        acc2[i][j] = __builtin_amdgcn_mfma_f32_16x16x32_bf16(AH[i], BX[j], acc2[i][j], 0, 0, 0);
        acc2[i][j] = __builtin_amdgcn_mfma_f32_16x16x32_bf16(AX[i], BH[j], acc2[i][j], 0, 0, 0);
        if (NPROD == 6)
          acc2[i][j] = __builtin_amdgcn_mfma_f32_16x16x32_bf16(AX[i], BX[j], acc2[i][j], 0, 0, 0);
      }
    __syncthreads();
  }

  // epilogue: C/D layout col = lane&15, row = (lane>>4)*4 + q
  const int fc = ln & 15;
  const int fr4 = (ln >> 4) << 2;
#pragma unroll
  for (int i = 0; i < FI; ++i) {
    const int rbase = m0 + wr * (BM / 2) + i * 16 + fr4;
#pragma unroll
    for (int j = 0; j < FJ; ++j) {
      const int c = n0 + wc * (BN / 2) + j * 16 + fc;
      const float bv = bias ? bias[c] : 0.0f;
#pragma unroll
      for (int q = 0; q < 4; ++q) {
        const float val = (acc1[i][j][q] + acc2[i][j][q]) * scale + bv;
        const long off = zC + (long)(rbase + q) * N + c;
        if (OUTMODE == 0) {
          C[off] = val;
        } else {
          const bf16 h = __float2bfloat16(val);
          const float r = val - __bfloat162float(h);
          const bf16 m = __float2bfloat16(r);
          Ch[off] = h; Cm[off] = m;
          Cl[off] = __float2bfloat16(r - __bfloat162float(m));
        }
      }
    }
  }
}

// ---------- radix-select top-64 + softmax + dense attn row ----------
__device__ __forceinline__ unsigned f2key(float f) {
  const unsigned u = __float_as_uint(f);
  return (u & 0x80000000u) ? ~u : (u | 0x80000000u);
}

__global__ __launch_bounds__(256) void topk_softmax_kernel(
    const float* __restrict__ scores, float* __restrict__ attn,
    int* __restrict__ tk_idx, float* __restrict__ tk_p) {
  const int row = blockIdx.x;  // 0..8191
  const int t = threadIdx.x, ln = t & 63, w = t >> 6;
  const float* srow = scores + (long)row * kS;

  __shared__ __align__(16) unsigned hist[2048];  // 8 KB; reused as lrow at the end
  __shared__ float s_wval[kTopK];
  __shared__ int s_wcol[kTopK];
  __shared__ unsigned wsum[4];
  __shared__ int s_cut, s_ngt, s_nw, s_ntie;
  __shared__ int s_tie[128];
  __shared__ float s_tieval;

  if (t == 0) { s_nw = 0; s_ntie = 0; }

  float val[8]; unsigned key[8];
  {
    const float4 q0 = ((const float4*)srow)[t];
    const float4 q1 = ((const float4*)srow)[t + 256];
    val[0] = q0.x; val[1] = q0.y; val[2] = q0.z; val[3] = q0.w;
    val[4] = q1.x; val[5] = q1.y; val[6] = q1.z; val[7] = q1.w;
  }
#pragma unroll
  for (int j = 0; j < 8; ++j) key[j] = f2key(val[j]);

  unsigned alive = 0xFFu, winner = 0u;
  int rem = kTopK, done = 0;

  for (int level = 0; level < 3; ++level) {
    const int shift = (level == 0) ? 21 : (level == 1) ? 10 : 0;
    const unsigned bmask = (level == 2) ? 0x3FFu : 0x7FFu;
    for (int i = t; i < 2048; i += 256) hist[i] = 0u;
    __syncthreads();
#pragma unroll
    for (int j = 0; j < 8; ++j)
      if (alive & (1u << j)) atomicAdd(&hist[(key[j] >> shift) & bmask], 1u);
    __syncthreads();

    unsigned h[8]; unsigned ts = 0u;
#pragma unroll
    for (int b = 0; b < 8; ++b) { h[b] = hist[8 * t + b]; ts += h[b]; }
    unsigned ss = ts;
#pragma unroll
    for (int off = 1; off < 64; off <<= 1) {
      const unsigned o = __shfl_down(ss, off);
      if (ln + off < 64) ss += o;
    }
    if (ln == 0) wsum[w] = ss;
    __syncthreads();
    unsigned run = ss - ts;
    for (int u = w + 1; u < 4; ++u) run += wsum[u];
#pragma unroll
    for (int b = 7; b >= 0; --b) {
      if (run < (unsigned)rem && run + h[b] >= (unsigned)rem) {
        s_cut = 8 * t + b;
        s_ngt = (int)run;
      }
      run += h[b];
    }
    __syncthreads();
    const int cut = s_cut;
    const int ngt = s_ngt;
    const int incut = (int)hist[cut];
    rem -= ngt;
#pragma unroll
    for (int j = 0; j < 8; ++j) {
      if (!(alive & (1u << j))) continue;
      const int b = (int)((key[j] >> shift) & bmask);
      if (b > cut) { winner |= 1u << j; alive &= ~(1u << j); }
      else if (b < cut) alive &= ~(1u << j);
    }
    if (incut == rem) {
      winner |= alive; alive = 0u; done = 1;
    } else if (level == 2) {
#pragma unroll
      for (int j = 0; j < 8; ++j)
        if (alive & (1u << j)) {
          const int pos = atomicAdd(&s_ntie, 1);
          const int col = (j < 4) ? (4 * t + j) : (1024 + 4 * t + j - 4);
          if (pos < 128) s_tie[pos] = col;
          s_tieval = val[j];
        }
      __syncthreads();
      if (w == 0) {
        volatile int* vt = s_tie;
        const int n = (s_ntie < 128) ? s_ntie : 128;
        const int take = (rem < n) ? rem : n;
        for (int it = 0; it < take; ++it) {
          int c0 = (ln < n) ? vt[ln] : 0x7FFFFFFF;
          int c1 = (ln + 64 < n) ? vt[ln + 64] : 0x7FFFFFFF;
          int bc, bs;
          if (c1 < c0) { bc = c1; bs = ln + 64; } else { bc = c0; bs = ln; }
#pragma unroll
          for (int off = 32; off; off >>= 1) {
            const int oc = __shfl_xor(bc, off);
            const int os = __shfl_xor(bs, off);
            if (oc < bc) { bc = oc; bs = os; }
          }
          if (ln == 0) {
            vt[bs] = 0x7FFFFFFF;
            const int p = s_nw;
            s_wcol[p] = bc; s_wval[p] = s_tieval;
            s_nw = p + 1;
          }
        }
      }
      alive = 0u;
      done = 1;
    }
    __syncthreads();
    if (done) break;
  }

#pragma unroll
  for (int j = 0; j < 8; ++j)
    if (winner & (1u << j)) {
      const int pos = atomicAdd(&s_nw, 1);
      const int col = (j < 4) ? (4 * t + j) : (1024 + 4 * t + j - 4);
      if (pos < kTopK) { s_wcol[pos] = col; s_wval[pos] = val[j]; }
    }
  __syncthreads();

  if (w == 0) {
    const float v = s_wval[ln];
    float m = v;
#pragma unroll
    for (int off = 32; off; off >>= 1) m = fmaxf(m, __shfl_xor(m, off));
    float p = expf(v - m);
    float Z = p;
#pragma unroll
    for (int off = 32; off; off >>= 1) Z += __shfl_xor(Z, off);
    p /= Z;
    s_wval[ln] = p;
    tk_idx[(long)row * kTopK + ln] = s_wcol[ln];
    tk_p[(long)row * kTopK + ln] = p;
  }
  __syncthreads();

  float* lrow = (float*)hist;
  ((float4*)lrow)[t] = make_float4(0.f, 0.f, 0.f, 0.f);
  ((float4*)lrow)[t + 256] = make_float4(0.f, 0.f, 0.f, 0.f);
  __syncthreads();
  if (t < kTopK) lrow[s_wcol[t]] = s_wval[t];
  __syncthreads();
  float4* dst = (float4*)(attn + (long)row * kS);
  dst[t] = ((const float4*)lrow)[t];
  dst[t + 256] = ((const float4*)lrow)[t + 256];
}

// ---------- mid[row,:] = sum_j p_j * V[idx_j,:] (fp32), emit bf16 h/m ----------
__global__ __launch_bounds__(256) void av_kernel(
    const float* __restrict__ V, const int* __restrict__ tk_idx,
    const float* __restrict__ tk_p, bf16* __restrict__ oh, bf16* __restrict__ om) {
  const int row = blockIdx.x;
  const int t = threadIdx.x;
  const int b = row >> 11;
  __shared__ int sidx[kTopK];
  __shared__ float sp[kTopK];
  if (t < kTopK) {
    sidx[t] = tk_idx[(long)row * kTopK + t];
    sp[t] = tk_p[(long)row * kTopK + t];
  }
  __syncthreads();
  const float* Vb = V + (long)b * kS * kD;
  float ax = 0.f, ay = 0.f;
  const int c = t * 2;
#pragma unroll 4
  for (int i = 0; i < kTopK; ++i) {
    const float2 vv = *(const float2*)(Vb + (long)sidx[i] * kD + c);
    ax = fmaf(sp[i], vv.x, ax);
    ay = fmaf(sp[i], vv.y, ay);
  }
  unsigned uh, um;
  {
    const bf16 hx = __float2bfloat16(ax);
    const float rx = ax - __bfloat162float(hx);
    const bf16 mx = __float2bfloat16(rx);
    const bf16 hy = __float2bfloat16(ay);
    const float ry = ay - __bfloat162float(hy);
    const bf16 my = __float2bfloat16(ry);
    uh = ((unsigned)__builtin_bit_cast(unsigned short, hy) << 16) | __builtin_bit_cast(unsigned short, hx);
    um = ((unsigned)__builtin_bit_cast(unsigned short, my) << 16) | __builtin_bit_cast(unsigned short, mx);
  }
  ((unsigned*)oh)[(long)row * (kD / 2) + t] = uh;
  ((unsigned*)om)[(long)row * (kD / 2) + t] = um;
}

extern "C" void kernel_launch(void* const* d_in, const int* in_sizes, int n_in,
                              void* d_out, int out_size, void* d_ws, size_t ws_size,
                              hipStream_t stream) {
  (void)in_sizes; (void)n_in; (void)out_size; (void)ws_size;
  const float* x = (const float*)d_in[0];
  const float* Wq = (const float*)d_in[1];
  const float* bq = (const float*)d_in[2];
  const float* Wk = (const float*)d_in[3];
  const float* bk = (const float*)d_in[4];
  const float* Wv = (const float*)d_in[5];
  const float* bv = (const float*)d_in[6];
  const float* Wo = (const float*)d_in[7];
  const float* bo = (const float*)d_in[8];

  float* out = (float*)d_out;             // [4,2048,512]
  float* attn = out + (long)kRows * kD;   // [4,2048,2048]

  const size_t SZ_ROWS = (size_t)kRows * kD * 2;  // 8 MB bf16 [8192,512]
  const size_t SZ_W = (size_t)kD * kD * 2;        // 512 KB bf16 [512,512]
  char* ws = (char*)d_ws;

  // region A (67.1 MB): x3 splits first, then scores overwrites (x3 dead by then)
  bf16* xh = (bf16*)(ws + 0);
  bf16* xm = (bf16*)(ws + SZ_ROWS);
  bf16* xl = (bf16*)(ws + 2 * SZ_ROWS);
  float* scores = (float*)(ws + 0);  // 4*2048*2048*4 = 67108864
  size_t off = 67108864;
  auto alloc = [&](size_t bytes) {
    void* p = ws + off;
    off += (bytes + 255) & ~(size_t)255;
    return p;
  };
  bf16* Wqh = (bf16*)alloc(SZ_W); bf16* Wqm = (bf16*)alloc(SZ_W); bf16* Wql = (bf16*)alloc(SZ_W);
  bf16* Wkh = (bf16*)alloc(SZ_W); bf16* Wkm = (bf16*)alloc(SZ_W); bf16* Wkl = (bf16*)alloc(SZ_W);
  bf16* Wvh = (bf16*)alloc(SZ_W); bf16* Wvm = (bf16*)alloc(SZ_W); bf16* Wvl = (bf16*)alloc(SZ_W);
  bf16* Woh = (bf16*)alloc(SZ_W); bf16* Wom = (bf16*)alloc(SZ_W); bf16* Wol = (bf16*)alloc(SZ_W);
  // region C (50.3 MB): Q3,K3; later reused for mid (Q3/K3 dead after scores gemm)
  char* regC = (char*)alloc(6 * SZ_ROWS);
  bf16* Qh = (bf16*)(regC);
  bf16* Qm = (bf16*)(regC + SZ_ROWS);
  bf16* Ql = (bf16*)(regC + 2 * SZ_ROWS);
  bf16* Kh = (bf16*)(regC + 3 * SZ_ROWS);
  bf16* Km = (bf16*)(regC + 4 * SZ_ROWS);
  bf16* Kl = (bf16*)(regC + 5 * SZ_ROWS);
  bf16* midh = (bf16*)(regC);
  bf16* midm = (bf16*)(regC + SZ_ROWS);
  // region D/E
  float* Vf = (float*)alloc((size_t)kRows * kD * 4);   // 16.8 MB
  int* tk_idx = (int*)alloc((size_t)kRows * kTopK * 4);
  float* tk_p = (float*)alloc((size_t)kRows * kTopK * 4);

  const float inv_sqrt_d = 1.0f / sqrtf((float)kD);

  // 1. 3-way splits (x + fused 4-weight)
  split3<<<2048, 256, 0, stream>>>(x, xh, xm, xl, kRows * kD);
  {
    WSplitArgs a;
    a.w[0] = Wq; a.w[1] = Wk; a.w[2] = Wv; a.w[3] = Wo;
    a.h[0] = Wqh; a.h[1] = Wkh; a.h[2] = Wvh; a.h[3] = Woh;
    a.m[0] = Wqm; a.m[1] = Wkm; a.m[2] = Wvm; a.m[3] = Wom;
    a.l[0] = Wql; a.l[1] = Wkl; a.l[2] = Wvl; a.l[3] = Wol;
    split3x4<<<dim3(128, 4), 256, 0, stream>>>(a, kD * kD);
  }

  // LDS sizes: NP*(BM+BN)*64 bytes
  const int LDS_P6 = 3 * (64 + 128) * 64;    // 36864 (Q/K proj)
  const int LDS_P3 = 2 * (64 + 128) * 64;    // 24576 (V/out proj)
  const int LDS_S = 3 * (128 + 128) * 64;    // 49152 (scores)
  const dim3 gProj(kD / 128, kRows / 64, 1);     // (4, 128)
  const dim3 gScore(kS / 128, kS / 128, kBatch); // (16, 16, 4)

  // 2. Q,K projections (6-product) -> bf16 h/m/l directly
  gemm_nt<1, 6, 64, 128><<<gProj, 256, LDS_P6, stream>>>(xh, xm, xl, Wqh, Wqm, Wql,
      nullptr, Qh, Qm, Ql, bq, 1.0f, kD, kD, 0, 0, 0);
  gemm_nt<1, 6, 64, 128><<<gProj, 256, LDS_P6, stream>>>(xh, xm, xl, Wkh, Wkm, Wkl,
      nullptr, Kh, Km, Kl, bk, 1.0f, kD, kD, 0, 0, 0);
  // 3. V projection (3-product) -> fp32
  gemm_nt<0, 3, 64, 128><<<gProj, 256, LDS_P3, stream>>>(xh, xm, xl, Wvh, Wvm, nullptr,
      Vf, nullptr, nullptr, nullptr, bv, 1.0f, kD, kD, 0, 0, 0);
  // 4. scores = (Q @ K^T) * inv_sqrt_d (6-product; overwrites region A)
  gemm_nt<0, 6, 128, 128><<<gScore, 256, LDS_S, stream>>>(Qh, Qm, Ql, Kh, Km, Kl,
      scores, nullptr, nullptr, nullptr, nullptr, inv_sqrt_d, kS, kD,
      (long)kS * kD, (long)kS * kD, (long)kS * kS);
  // 5. radix-select top-64 + softmax + dense attn
  topk_softmax_kernel<<<kRows, 256, 0, stream>>>(scores, attn, tk_idx, tk_p);
  // 6. mid = attn @ V (sparse gather) -> bf16 h/m (region C; Q3/K3 dead)
  av_kernel<<<kRows, 256, 0, stream>>>(Vf, tk_idx, tk_p, midh, midm);
  // 7. final projection (3-product) -> d_out
  gemm_nt<0, 3, 64, 128><<<gProj, 256, LDS_P3, stream>>>(midh, midm, nullptr, Woh, Wom, nullptr,
      out, nullptr, nullptr, nullptr, bo, 1.0f, kD, kD, 0, 0, 0);
}

// Round 5
// 298.220 us; speedup vs baseline: 2.9882x; 1.0415x over previous
//
#include <hip/hip_runtime.h>
#include <hip/hip_bf16.h>
#include <math.h>

#define AS1 __attribute__((address_space(1)))
#define AS3 __attribute__((address_space(3)))

typedef __attribute__((ext_vector_type(8))) short bf16x8;
typedef __attribute__((ext_vector_type(4))) float f32x4;
typedef __hip_bfloat16 bf16;

namespace {
constexpr int kBatch = 4, kS = 2048, kD = 512;
constexpr int kRows = kBatch * kS;   // 8192
constexpr int kTopK = 64;
}

__device__ __forceinline__ void async16(void* lds, const void* g) {
  // global->LDS direct, 16B/lane; LDS dest is wave-uniform base + lane*16
  __builtin_amdgcn_global_load_lds((AS1 void*)g, (AS3 void*)lds, 16, 0, 0);
}

template<int N> __device__ __forceinline__ void waitcnt_vm() {
  if constexpr (N == 6) asm volatile("s_waitcnt vmcnt(6)" ::: "memory");
  else if constexpr (N == 9) asm volatile("s_waitcnt vmcnt(9)" ::: "memory");
  else asm volatile("s_waitcnt vmcnt(0)" ::: "memory");
}

// ---------- fp32 -> bf16 h/m/l 3-way split ----------
__global__ __launch_bounds__(256) void split3(
    const float* __restrict__ in, bf16* __restrict__ h, bf16* __restrict__ m,
    bf16* __restrict__ l, int n) {
  int i = blockIdx.x * 256 + threadIdx.x;
  const int stride = gridDim.x * 256;
  for (; i < n; i += stride) {
    const float x = in[i];
    const bf16 hh = __float2bfloat16(x);
    const float r = x - __bfloat162float(hh);
    const bf16 mm = __float2bfloat16(r);
    const float r2 = r - __bfloat162float(mm);
    h[i] = hh; m[i] = mm; l[i] = __float2bfloat16(r2);
  }
}

struct WSplitArgs {
  const float* w[4];
  bf16* h[4]; bf16* m[4]; bf16* l[4];
};
__global__ __launch_bounds__(256) void split3x4(WSplitArgs a, int n) {
  const int g = blockIdx.y;
  const float* in = a.w[g];
  bf16* h = a.h[g]; bf16* m = a.m[g]; bf16* l = a.l[g];
  int i = blockIdx.x * 256 + threadIdx.x;
  const int stride = gridDim.x * 256;
  for (; i < n; i += stride) {
    const float x = in[i];
    const bf16 hh = __float2bfloat16(x);
    const float r = x - __bfloat162float(hh);
    const bf16 mm = __float2bfloat16(r);
    const float r2 = r - __bfloat162float(mm);
    h[i] = hh; m[i] = mm; l[i] = __float2bfloat16(r2);
  }
}

// ---------- pipelined C[M,N] = scale*(A @ B^T) + bias, split-bf16 precision ----------
// Double-buffered LDS + counted vmcnt (T3/T4): per K-step issue next-tile
// global_load_lds, wait vmcnt(CALLS) (prev tile landed, next stays in flight),
// raw s_barrier, compute, lgkmcnt(0), raw s_barrier. No vmcnt(0) in the loop.
// LDS per piece: [superrow s=2rows][8 chunks 16B], phys chunk = logical ^ (s&7),
// achieved by pre-swizzling the per-lane GLOBAL source (LDS dest stays linear).
template<int OUTMODE, int NPROD, int BM, int BN, int WAVES_M, int WAVES_N>
__global__ __launch_bounds__(64 * WAVES_M * WAVES_N, 2) void gemm_pipe(
    const bf16* __restrict__ Ah, const bf16* __restrict__ Am, const bf16* __restrict__ Al,
    const bf16* __restrict__ Bh, const bf16* __restrict__ Bm, const bf16* __restrict__ Bl,
    float* __restrict__ C, bf16* __restrict__ Ch, bf16* __restrict__ Cm, bf16* __restrict__ Cl,
    const float* __restrict__ bias, float scale, int N, int K,
    long batchA, long batchB, long batchC) {
  constexpr int NP = (NPROD == 6) ? 3 : 2;
  constexpr int T = 64 * WAVES_M * WAVES_N;
  constexpr int WM = BM / WAVES_M, WN = BN / WAVES_N;
  constexpr int FI = WM / 16, FJ = WN / 16;
  constexpr int ABYTES = BM * 64, BBYTES = BN * 64;
  constexpr int HALF = NP * (ABYTES + BBYTES);
  constexpr int SPAN = T * 16;
  constexpr int CALLS = HALF / SPAN;
  static_assert(HALF % SPAN == 0, "staging must be whole call-spans");
  extern __shared__ char smem[];

  const int t = threadIdx.x;
  const int wi = t >> 6, ln = t & 63;
  const int wr = wi / WAVES_N, wc = wi % WAVES_N;

  // bijective XCD-chunked block swizzle (grid size % 8 == 0)
  int bx, by, bz;
  {
    const int F = blockIdx.x + gridDim.x * (blockIdx.y + gridDim.y * blockIdx.z);
    const int cpx = (gridDim.x * gridDim.y * gridDim.z) >> 3;
    const int L = (F & 7) * cpx + (F >> 3);
    bx = L % gridDim.x;
    const int r = L / gridDim.x;
    by = r % gridDim.y; bz = r / gridDim.y;
  }
  const int m0 = by * BM, n0 = bx * BN;
  const long zA = (long)bz * batchA;
  const long zB = (long)bz * batchB;
  const long zC = (long)bz * batchC;

  // ---- per-lane staging sources (pre-swizzled; piece-boundary aware) ----
  const bf16* gp[CALLS];
#pragma unroll
  for (int q = 0; q < CALLS; ++q) {
    const int o = q * SPAN + t * 16;  // dest byte within the K-step region
    const bf16* base; long rbase; int local;
    if (o < NP * ABYTES) {
      const int p = o / ABYTES; local = o % ABYTES;
      base = (p == 0) ? Ah : (p == 1) ? Am : Al;
      rbase = zA + (long)m0 * K;
    } else {
      const int o2 = o - NP * ABYTES;
      const int p = o2 / BBYTES; local = o2 % BBYTES;
      base = (p == 0) ? Bh : (p == 1) ? Bm : Bl;
      rbase = zB + (long)n0 * K;
    }
    const int s = local >> 7;
    const int pc = (local >> 4) & 7;
    const int lc = pc ^ (s & 7);
    const int row = 2 * s + (lc >> 2);
    const int ke = (lc & 3) << 3;
    gp[q] = base + rbase + (long)row * K + ke;
  }
  const int lofs = wi * 1024;  // wave-uniform LDS base within each call-span

  // ---- fragment read offsets (bytes within a piece) ----
  const int fr = ln & 15, cc = ln >> 4;
  const int c2 = ((fr & 1) << 2) | cc;
  int aoff[FI], boff[FJ];
#pragma unroll
  for (int i = 0; i < FI; ++i) {
    const int s = (wr * WM + i * 16 + fr) >> 1;
    aoff[i] = s * 128 + ((c2 ^ (s & 7)) << 4);
  }
#pragma unroll
  for (int j = 0; j < FJ; ++j) {
    const int s = (wc * WN + j * 16 + fr) >> 1;
    boff[j] = s * 128 + ((c2 ^ (s & 7)) << 4);
  }

  f32x4 acc1[FI][FJ] = {}, acc2[FI][FJ] = {};

  auto STAGE = [&](int buf, int kt) {
#pragma unroll
    for (int q = 0; q < CALLS; ++q)
      async16(smem + buf * HALF + q * SPAN + lofs, gp[q] + kt);
  };

  auto COMPUTE = [&](const char* rb) {
    bf16x8 AH[FI], BH[FJ], AX[FI], BX[FJ];
#pragma unroll
    for (int i = 0; i < FI; ++i) AH[i] = *(const bf16x8*)(rb + aoff[i]);
#pragma unroll
    for (int j = 0; j < FJ; ++j) BH[j] = *(const bf16x8*)(rb + NP * ABYTES + boff[j]);
#pragma unroll
    for (int i = 0; i < FI; ++i)
#pragma unroll
      for (int j = 0; j < FJ; ++j)
        acc1[i][j] = __builtin_amdgcn_mfma_f32_16x16x32_bf16(AH[i], BH[j], acc1[i][j], 0, 0, 0);
    if constexpr (NPROD == 6) {  // l-group: hl + lh
#pragma unroll
      for (int i = 0; i < FI; ++i) AX[i] = *(const bf16x8*)(rb + 2 * ABYTES + aoff[i]);
#pragma unroll
      for (int j = 0; j < FJ; ++j) BX[j] = *(const bf16x8*)(rb + NP * ABYTES + 2 * BBYTES + boff[j]);
#pragma unroll
      for (int i = 0; i < FI; ++i)
#pragma unroll
        for (int j = 0; j < FJ; ++j) {
          acc2[i][j] = __builtin_amdgcn_mfma_f32_16x16x32_bf16(AH[i], BX[j], acc2[i][j], 0, 0, 0);
          acc2[i][j] = __builtin_amdgcn_mfma_f32_16x16x32_bf16(AX[i], BH[j], acc2[i][j], 0, 0, 0);
        }
    }
    // m-group: hm + mh (+ mm when NPROD==6)
#pragma unroll
    for (int i = 0; i < FI; ++i) AX[i] = *(const bf16x8*)(rb + 1 * ABYTES + aoff[i]);
#pragma unroll
    for (int j = 0; j < FJ; ++j) BX[j] = *(const bf16x8*)(rb + NP * ABYTES + 1 * BBYTES + boff[j]);
#pragma unroll
    for (int i = 0; i < FI; ++i)
#pragma unroll
      for (int j = 0; j < FJ; ++j) {
        acc2[i][j] = __builtin_amdgcn_mfma_f32_16x16x32_bf16(AH[i], BX[j], acc2[i][j], 0, 0, 0);
        acc2[i][j] = __builtin_amdgcn_mfma_f32_16x16x32_bf16(AX[i], BH[j], acc2[i][j], 0, 0, 0);
        if constexpr (NPROD == 6)
          acc2[i][j] = __builtin_amdgcn_mfma_f32_16x16x32_bf16(AX[i], BX[j], acc2[i][j], 0, 0, 0);
      }
  };

  // ---- pipelined K-loop ----
  STAGE(0, 0);
  int cur = 0;
  for (int kt = 32; kt < K; kt += 32) {
    STAGE(cur ^ 1, kt);          // next tile in flight
    waitcnt_vm<CALLS>();         // current tile landed (next stays outstanding)
    __builtin_amdgcn_s_barrier();
    COMPUTE(smem + cur * HALF);
    asm volatile("s_waitcnt lgkmcnt(0)" ::: "memory");  // reads done before overwrite
    __builtin_amdgcn_s_barrier();
    cur ^= 1;
  }
  waitcnt_vm<0>();
  __builtin_amdgcn_s_barrier();
  COMPUTE(smem + cur * HALF);

  // ---- epilogue: C/D layout col = lane&15, row = (lane>>4)*4 + q ----
  const int fc = ln & 15;
  const int fr4 = (ln >> 4) << 2;
#pragma unroll
  for (int i = 0; i < FI; ++i) {
    const int rbase = m0 + wr * WM + i * 16 + fr4;
#pragma unroll
    for (int j = 0; j < FJ; ++j) {
      const int c = n0 + wc * WN + j * 16 + fc;
      const float bv = bias ? bias[c] : 0.0f;
#pragma unroll
      for (int q = 0; q < 4; ++q) {
        const float val = (acc1[i][j][q] + acc2[i][j][q]) * scale + bv;
        const long off = zC + (long)(rbase + q) * N + c;
        if (OUTMODE == 0) {
          C[off] = val;
        } else {
          const bf16 h = __float2bfloat16(val);
          const float r = val - __bfloat162float(h);
          const bf16 m = __float2bfloat16(r);
          Ch[off] = h; Cm[off] = m;
          Cl[off] = __float2bfloat16(r - __bfloat162float(m));
        }
      }
    }
  }
}

// ---------- radix-select top-64 + softmax + dense attn row ----------
__device__ __forceinline__ unsigned f2key(float f) {
  const unsigned u = __float_as_uint(f);
  return (u & 0x80000000u) ? ~u : (u | 0x80000000u);
}

__global__ __launch_bounds__(256) void topk_softmax_kernel(
    const float* __restrict__ scores, float* __restrict__ attn,
    int* __restrict__ tk_idx, float* __restrict__ tk_p) {
  const int row = blockIdx.x;  // 0..8191
  const int t = threadIdx.x, ln = t & 63, w = t >> 6;
  const float* srow = scores + (long)row * kS;

  __shared__ __align__(16) unsigned hist[2048];  // 8 KB; reused as lrow at the end
  __shared__ float s_wval[kTopK];
  __shared__ int s_wcol[kTopK];
  __shared__ unsigned wsum[4];
  __shared__ int s_cut, s_ngt, s_nw, s_ntie;
  __shared__ int s_tie[128];
  __shared__ float s_tieval;

  if (t == 0) { s_nw = 0; s_ntie = 0; }

  float val[8]; unsigned key[8];
  {
    const float4 q0 = ((const float4*)srow)[t];
    const float4 q1 = ((const float4*)srow)[t + 256];
    val[0] = q0.x; val[1] = q0.y; val[2] = q0.z; val[3] = q0.w;
    val[4] = q1.x; val[5] = q1.y; val[6] = q1.z; val[7] = q1.w;
  }
#pragma unroll
  for (int j = 0; j < 8; ++j) key[j] = f2key(val[j]);

  unsigned alive = 0xFFu, winner = 0u;
  int rem = kTopK, done = 0;

  for (int level = 0; level < 3; ++level) {
    const int shift = (level == 0) ? 21 : (level == 1) ? 10 : 0;
    const unsigned bmask = (level == 2) ? 0x3FFu : 0x7FFu;
    for (int i = t; i < 2048; i += 256) hist[i] = 0u;
    __syncthreads();
#pragma unroll
    for (int j = 0; j < 8; ++j)
      if (alive & (1u << j)) atomicAdd(&hist[(key[j] >> shift) & bmask], 1u);
    __syncthreads();

    unsigned h[8]; unsigned ts = 0u;
#pragma unroll
    for (int b = 0; b < 8; ++b) { h[b] = hist[8 * t + b]; ts += h[b]; }
    unsigned ss = ts;
#pragma unroll
    for (int off = 1; off < 64; off <<= 1) {
      const unsigned o = __shfl_down(ss, off);
      if (ln + off < 64) ss += o;
    }
    if (ln == 0) wsum[w] = ss;
    __syncthreads();
    unsigned run = ss - ts;
    for (int u = w + 1; u < 4; ++u) run += wsum[u];
#pragma unroll
    for (int b = 7; b >= 0; --b) {
      if (run < (unsigned)rem && run + h[b] >= (unsigned)rem) {
        s_cut = 8 * t + b;
        s_ngt = (int)run;
      }
      run += h[b];
    }
    __syncthreads();
    const int cut = s_cut;
    const int ngt = s_ngt;
    const int incut = (int)hist[cut];
    rem -= ngt;
#pragma unroll
    for (int j = 0; j < 8; ++j) {
      if (!(alive & (1u << j))) continue;
      const int b = (int)((key[j] >> shift) & bmask);
      if (b > cut) { winner |= 1u << j; alive &= ~(1u << j); }
      else if (b < cut) alive &= ~(1u << j);
    }
    if (incut == rem) {
      winner |= alive; alive = 0u; done = 1;
    } else if (level == 2) {
#pragma unroll
      for (int j = 0; j < 8; ++j)
        if (alive & (1u << j)) {
          const int pos = atomicAdd(&s_ntie, 1);
          const int col = (j < 4) ? (4 * t + j) : (1024 + 4 * t + j - 4);
          if (pos < 128) s_tie[pos] = col;
          s_tieval = val[j];
        }
      __syncthreads();
      if (w == 0) {
        volatile int* vt = s_tie;
        const int n = (s_ntie < 128) ? s_ntie : 128;
        const int take = (rem < n) ? rem : n;
        for (int it = 0; it < take; ++it) {
          int c0 = (ln < n) ? vt[ln] : 0x7FFFFFFF;
          int c1 = (ln + 64 < n) ? vt[ln + 64] : 0x7FFFFFFF;
          int bc, bs;
          if (c1 < c0) { bc = c1; bs = ln + 64; } else { bc = c0; bs = ln; }
#pragma unroll
          for (int off = 32; off; off >>= 1) {
            const int oc = __shfl_xor(bc, off);
            const int os = __shfl_xor(bs, off);
            if (oc < bc) { bc = oc; bs = os; }
          }
          if (ln == 0) {
            vt[bs] = 0x7FFFFFFF;
            const int p = s_nw;
            s_wcol[p] = bc; s_wval[p] = s_tieval;
            s_nw = p + 1;
          }
        }
      }
      alive = 0u;
      done = 1;
    }
    __syncthreads();
    if (done) break;
  }

#pragma unroll
  for (int j = 0; j < 8; ++j)
    if (winner & (1u << j)) {
      const int pos = atomicAdd(&s_nw, 1);
      const int col = (j < 4) ? (4 * t + j) : (1024 + 4 * t + j - 4);
      if (pos < kTopK) { s_wcol[pos] = col; s_wval[pos] = val[j]; }
    }
  __syncthreads();

  if (w == 0) {
    const float v = s_wval[ln];
    float m = v;
#pragma unroll
    for (int off = 32; off; off >>= 1) m = fmaxf(m, __shfl_xor(m, off));
    float p = expf(v - m);
    float Z = p;
#pragma unroll
    for (int off = 32; off; off >>= 1) Z += __shfl_xor(Z, off);
    p /= Z;
    s_wval[ln] = p;
    tk_idx[(long)row * kTopK + ln] = s_wcol[ln];
    tk_p[(long)row * kTopK + ln] = p;
  }
  __syncthreads();

  float* lrow = (float*)hist;
  ((float4*)lrow)[t] = make_float4(0.f, 0.f, 0.f, 0.f);
  ((float4*)lrow)[t + 256] = make_float4(0.f, 0.f, 0.f, 0.f);
  __syncthreads();
  if (t < kTopK) lrow[s_wcol[t]] = s_wval[t];
  __syncthreads();
  float4* dst = (float4*)(attn + (long)row * kS);
  dst[t] = ((const float4*)lrow)[t];
  dst[t + 256] = ((const float4*)lrow)[t + 256];
}

// ---------- mid[row,:] = sum_j p_j * V[idx_j,:] (fp32), emit bf16 h/m ----------
__global__ __launch_bounds__(256) void av_kernel(
    const float* __restrict__ V, const int* __restrict__ tk_idx,
    const float* __restrict__ tk_p, bf16* __restrict__ oh, bf16* __restrict__ om) {
  const int row = blockIdx.x;
  const int t = threadIdx.x;
  const int b = row >> 11;
  __shared__ int sidx[kTopK];
  __shared__ float sp[kTopK];
  if (t < kTopK) {
    sidx[t] = tk_idx[(long)row * kTopK + t];
    sp[t] = tk_p[(long)row * kTopK + t];
  }
  __syncthreads();
  const float* Vb = V + (long)b * kS * kD;
  float ax = 0.f, ay = 0.f;
  const int c = t * 2;
#pragma unroll 4
  for (int i = 0; i < kTopK; ++i) {
    const float2 vv = *(const float2*)(Vb + (long)sidx[i] * kD + c);
    ax = fmaf(sp[i], vv.x, ax);
    ay = fmaf(sp[i], vv.y, ay);
  }
  unsigned uh, um;
  {
    const bf16 hx = __float2bfloat16(ax);
    const float rx = ax - __bfloat162float(hx);
    const bf16 mx = __float2bfloat16(rx);
    const bf16 hy = __float2bfloat16(ay);
    const float ry = ay - __bfloat162float(hy);
    const bf16 my = __float2bfloat16(ry);
    uh = ((unsigned)__builtin_bit_cast(unsigned short, hy) << 16) | __builtin_bit_cast(unsigned short, hx);
    um = ((unsigned)__builtin_bit_cast(unsigned short, my) << 16) | __builtin_bit_cast(unsigned short, mx);
  }
  ((unsigned*)oh)[(long)row * (kD / 2) + t] = uh;
  ((unsigned*)om)[(long)row * (kD / 2) + t] = um;
}

extern "C" void kernel_launch(void* const* d_in, const int* in_sizes, int n_in,
                              void* d_out, int out_size, void* d_ws, size_t ws_size,
                              hipStream_t stream) {
  (void)in_sizes; (void)n_in; (void)out_size; (void)ws_size;
  const float* x = (const float*)d_in[0];
  const float* Wq = (const float*)d_in[1];
  const float* bq = (const float*)d_in[2];
  const float* Wk = (const float*)d_in[3];
  const float* bk = (const float*)d_in[4];
  const float* Wv = (const float*)d_in[5];
  const float* bv = (const float*)d_in[6];
  const float* Wo = (const float*)d_in[7];
  const float* bo = (const float*)d_in[8];

  float* out = (float*)d_out;             // [4,2048,512]
  float* attn = out + (long)kRows * kD;   // [4,2048,2048]

  const size_t SZ_ROWS = (size_t)kRows * kD * 2;  // 8 MB bf16 [8192,512]
  const size_t SZ_W = (size_t)kD * kD * 2;        // 512 KB bf16 [512,512]
  char* ws = (char*)d_ws;

  // region A (67.1 MB): x3 splits first, then scores overwrites (x3 dead by then)
  bf16* xh = (bf16*)(ws + 0);
  bf16* xm = (bf16*)(ws + SZ_ROWS);
  bf16* xl = (bf16*)(ws + 2 * SZ_ROWS);
  float* scores = (float*)(ws + 0);  // 4*2048*2048*4 = 67108864
  size_t off = 67108864;
  auto alloc = [&](size_t bytes) {
    void* p = ws + off;
    off += (bytes + 255) & ~(size_t)255;
    return p;
  };
  bf16* Wqh = (bf16*)alloc(SZ_W); bf16* Wqm = (bf16*)alloc(SZ_W); bf16* Wql = (bf16*)alloc(SZ_W);
  bf16* Wkh = (bf16*)alloc(SZ_W); bf16* Wkm = (bf16*)alloc(SZ_W); bf16* Wkl = (bf16*)alloc(SZ_W);
  bf16* Wvh = (bf16*)alloc(SZ_W); bf16* Wvm = (bf16*)alloc(SZ_W);
  bf16* Woh = (bf16*)alloc(SZ_W); bf16* Wom = (bf16*)alloc(SZ_W);
  bf16* Wvl = (bf16*)alloc(SZ_W); bf16* Wol = (bf16*)alloc(SZ_W);  // staged but unused in 3-prod
  // region C (50.3 MB): Q3,K3; later reused for mid (Q3/K3 dead after scores gemm)
  char* regC = (char*)alloc(6 * SZ_ROWS);
  bf16* Qh = (bf16*)(regC);
  bf16* Qm = (bf16*)(regC + SZ_ROWS);
  bf16* Ql = (bf16*)(regC + 2 * SZ_ROWS);
  bf16* Kh = (bf16*)(regC + 3 * SZ_ROWS);
  bf16* Km = (bf16*)(regC + 4 * SZ_ROWS);
  bf16* Kl = (bf16*)(regC + 5 * SZ_ROWS);
  bf16* midh = (bf16*)(regC);
  bf16* midm = (bf16*)(regC + SZ_ROWS);
  // region D/E
  float* Vf = (float*)alloc((size_t)kRows * kD * 4);   // 16.8 MB
  int* tk_idx = (int*)alloc((size_t)kRows * kTopK * 4);
  float* tk_p = (float*)alloc((size_t)kRows * kTopK * 4);

  const float inv_sqrt_d = 1.0f / sqrtf((float)kD);

  // 1. 3-way splits (x + fused 4-weight)
  split3<<<2048, 256, 0, stream>>>(x, xh, xm, xl, kRows * kD);
  {
    WSplitArgs a;
    a.w[0] = Wq; a.w[1] = Wk; a.w[2] = Wv; a.w[3] = Wo;
    a.h[0] = Wqh; a.h[1] = Wkh; a.h[2] = Wvh; a.h[3] = Woh;
    a.m[0] = Wqm; a.m[1] = Wkm; a.m[2] = Wvm; a.m[3] = Wom;
    a.l[0] = Wql; a.l[1] = Wkl; a.l[2] = Wvl; a.l[3] = Wol;
    split3x4<<<dim3(128, 4), 256, 0, stream>>>(a, kD * kD);
  }

  // double-buffered LDS sizes: 2 * NP*(BM+BN)*64
  const int LDS_P6 = 2 * 3 * (128 + 64) * 64;   // 73728  (Q/K proj)
  const int LDS_P3 = 2 * 2 * (128 + 64) * 64;   // 49152  (V/out proj)
  const int LDS_S  = 2 * 3 * (256 + 128) * 64;  // 147456 (scores)
  const dim3 gProj(kD / 64, kRows / 128, 1);      // (8, 128) = 1024? no: (8,64)? -> computed below
  const dim3 gProj2(kD / 64, kRows / 128, 1);     // unused (kept for clarity)
  const dim3 gP(kD / 64, kRows / 128, 1);         // (8, 64, 1) = 512 blocks
  const dim3 gScore(kS / 128, kS / 256, kBatch);  // (16, 8, 4) = 512 blocks

  // 2. Q,K projections (6-product, BM128/BN64, 4 waves) -> bf16 h/m/l directly
  gemm_pipe<1, 6, 128, 64, 2, 2><<<gP, 256, LDS_P6, stream>>>(xh, xm, xl, Wqh, Wqm, Wql,
      nullptr, Qh, Qm, Ql, bq, 1.0f, kD, kD, 0, 0, 0);
  gemm_pipe<1, 6, 128, 64, 2, 2><<<gP, 256, LDS_P6, stream>>>(xh, xm, xl, Wkh, Wkm, Wkl,
      nullptr, Kh, Km, Kl, bk, 1.0f, kD, kD, 0, 0, 0);
  // 3. V projection (3-product) -> fp32
  gemm_pipe<0, 3, 128, 64, 2, 2><<<gP, 256, LDS_P3, stream>>>(xh, xm, nullptr, Wvh, Wvm, nullptr,
      Vf, nullptr, nullptr, nullptr, bv, 1.0f, kD, kD, 0, 0, 0);
  // 4. scores = (Q @ K^T) * inv_sqrt_d (6-product, BM256/BN128, 8 waves)
  gemm_pipe<0, 6, 256, 128, 4, 2><<<gScore, 512, LDS_S, stream>>>(Qh, Qm, Ql, Kh, Km, Kl,
      scores, nullptr, nullptr, nullptr, nullptr, inv_sqrt_d, kS, kD,
      (long)kS * kD, (long)kS * kD, (long)kS * kS);
  // 5. radix-select top-64 + softmax + dense attn
  topk_softmax_kernel<<<kRows, 256, 0, stream>>>(scores, attn, tk_idx, tk_p);
  // 6. mid = attn @ V (sparse gather) -> bf16 h/m (region C; Q3/K3 dead)
  av_kernel<<<kRows, 256, 0, stream>>>(Vf, tk_idx, tk_p, midh, midm);
  // 7. final projection (3-product) -> d_out
  gemm_pipe<0, 3, 128, 64, 2, 2><<<gP, 256, LDS_P3, stream>>>(midh, midm, nullptr, Woh, Wom, nullptr,
      out, nullptr, nullptr, nullptr, bo, 1.0f, kD, kD, 0, 0, 0);
}

// Round 7
// 283.495 us; speedup vs baseline: 3.1434x; 1.0519x over previous
//
#include <hip/hip_runtime.h>
#include <hip/hip_bf16.h>
#include <math.h>

#define AS1 __attribute__((address_space(1)))
#define AS3 __attribute__((address_space(3)))

typedef __attribute__((ext_vector_type(8))) short bf16x8;
typedef __attribute__((ext_vector_type(4))) float f32x4;
typedef __hip_bfloat16 bf16;

namespace {
constexpr int kBatch = 4, kS = 2048, kD = 512;
constexpr int kRows = kBatch * kS;   // 8192
constexpr int kTopK = 64;
}

__device__ __forceinline__ void async16(void* lds, const void* g) {
  __builtin_amdgcn_global_load_lds((AS1 void*)g, (AS3 void*)lds, 16, 0, 0);
}

// ---------- fp32 -> bf16 h/m/l 3-way split ----------
__global__ __launch_bounds__(256) void split3(
    const float* __restrict__ in, bf16* __restrict__ h, bf16* __restrict__ m,
    bf16* __restrict__ l, int n) {
  int i = blockIdx.x * 256 + threadIdx.x;
  const int stride = gridDim.x * 256;
  for (; i < n; i += stride) {
    const float x = in[i];
    const bf16 hh = __float2bfloat16(x);
    const float r = x - __bfloat162float(hh);
    const bf16 mm = __float2bfloat16(r);
    const float r2 = r - __bfloat162float(mm);
    h[i] = hh; m[i] = mm; l[i] = __float2bfloat16(r2);
  }
}

struct WSplitArgs {
  const float* w[4];
  bf16* h[4]; bf16* m[4]; bf16* l[4];
};
__global__ __launch_bounds__(256) void split3x4(WSplitArgs a, int n) {
  const int g = blockIdx.y;
  const float* in = a.w[g];
  bf16* h = a.h[g]; bf16* m = a.m[g]; bf16* l = a.l[g];
  int i = blockIdx.x * 256 + threadIdx.x;
  const int stride = gridDim.x * 256;
  for (; i < n; i += stride) {
    const float x = in[i];
    const bf16 hh = __float2bfloat16(x);
    const float r = x - __bfloat162float(hh);
    const bf16 mm = __float2bfloat16(r);
    const float r2 = r - __bfloat162float(mm);
    h[i] = hh; m[i] = mm; l[i] = __float2bfloat16(r2);
  }
}

// ---------- pipelined C[M,N] = scale*(A @ B^T) + bias, split-bf16 precision ----------
// PROVEN round-5 structure (passed post-timing): dbuf LDS + counted vmcnt,
// one STAGE + one monolithic COMPUTE per K-step, two raw barriers.
// OUTMODE 0: fp32 C; 1: h/m/l split out; 2: h/m split out.
template<int OUTMODE, int NPROD, int BM, int BN, int WAVES_M, int WAVES_N>
__global__ __launch_bounds__(64 * WAVES_M * WAVES_N, 2) void gemm_pipe(
    const bf16* __restrict__ Ah, const bf16* __restrict__ Am, const bf16* __restrict__ Al,
    const bf16* __restrict__ Bh, const bf16* __restrict__ Bm, const bf16* __restrict__ Bl,
    float* __restrict__ C, bf16* __restrict__ Ch, bf16* __restrict__ Cm, bf16* __restrict__ Cl,
    const float* __restrict__ bias, float scale, int N, int K,
    long batchA, long batchB, long batchC) {
  constexpr int NP = (NPROD == 6) ? 3 : 2;
  constexpr int T = 64 * WAVES_M * WAVES_N;
  constexpr int WM = BM / WAVES_M, WN = BN / WAVES_N;
  constexpr int FI = WM / 16, FJ = WN / 16;
  constexpr int ABYTES = BM * 64, BBYTES = BN * 64;
  constexpr int HALF = NP * (ABYTES + BBYTES);
  constexpr int SPAN = T * 16;
  constexpr int CALLS = HALF / SPAN;
  static_assert(HALF % SPAN == 0, "staging must be whole call-spans");
  extern __shared__ char smem[];

  const int t = threadIdx.x;
  const int wi = t >> 6, ln = t & 63;
  const int wr = wi / WAVES_N, wc = wi % WAVES_N;

  int bx, by, bz;
  {
    const int F = blockIdx.x + gridDim.x * (blockIdx.y + gridDim.y * blockIdx.z);
    const int cpx = (gridDim.x * gridDim.y * gridDim.z) >> 3;
    const int L = (F & 7) * cpx + (F >> 3);
    bx = L % gridDim.x;
    const int r = L / gridDim.x;
    by = r % gridDim.y; bz = r / gridDim.y;
  }
  const int m0 = by * BM, n0 = bx * BN;
  const long zA = (long)bz * batchA;
  const long zB = (long)bz * batchB;
  const long zC = (long)bz * batchC;

  const bf16* gp[CALLS];
#pragma unroll
  for (int q = 0; q < CALLS; ++q) {
    const int o = q * SPAN + t * 16;
    const bf16* base; long rbase; int local;
    if (o < NP * ABYTES) {
      const int p = o / ABYTES; local = o % ABYTES;
      base = (p == 0) ? Ah : (p == 1) ? Am : Al;
      rbase = zA + (long)m0 * K;
    } else {
      const int o2 = o - NP * ABYTES;
      const int p = o2 / BBYTES; local = o2 % BBYTES;
      base = (p == 0) ? Bh : (p == 1) ? Bm : Bl;
      rbase = zB + (long)n0 * K;
    }
    const int s = local >> 7;
    const int pc = (local >> 4) & 7;
    const int lc = pc ^ (s & 7);
    const int row = 2 * s + (lc >> 2);
    const int ke = (lc & 3) << 3;
    gp[q] = base + rbase + (long)row * K + ke;
  }
  const int lofs = wi * 1024;

  const int fr = ln & 15, cc = ln >> 4;
  const int c2 = ((fr & 1) << 2) | cc;
  int aoff[FI], boff[FJ];
#pragma unroll
  for (int i = 0; i < FI; ++i) {
    const int s = (wr * WM + i * 16 + fr) >> 1;
    aoff[i] = s * 128 + ((c2 ^ (s & 7)) << 4);
  }
#pragma unroll
  for (int j = 0; j < FJ; ++j) {
    const int s = (wc * WN + j * 16 + fr) >> 1;
    boff[j] = s * 128 + ((c2 ^ (s & 7)) << 4);
  }

  f32x4 acc1[FI][FJ] = {}, acc2[FI][FJ] = {};

  auto STAGE = [&](int buf, int kt) {
#pragma unroll
    for (int q = 0; q < CALLS; ++q)
      async16(smem + buf * HALF + q * SPAN + lofs, gp[q] + kt);
  };

  auto COMPUTE = [&](const char* rb) {
    bf16x8 AH[FI], BH[FJ], AX[FI], BX[FJ];
#pragma unroll
    for (int i = 0; i < FI; ++i) AH[i] = *(const bf16x8*)(rb + aoff[i]);
#pragma unroll
    for (int j = 0; j < FJ; ++j) BH[j] = *(const bf16x8*)(rb + NP * ABYTES + boff[j]);
#pragma unroll
    for (int i = 0; i < FI; ++i)
#pragma unroll
      for (int j = 0; j < FJ; ++j)
        acc1[i][j] = __builtin_amdgcn_mfma_f32_16x16x32_bf16(AH[i], BH[j], acc1[i][j], 0, 0, 0);
    if constexpr (NPROD == 6) {
#pragma unroll
      for (int i = 0; i < FI; ++i) AX[i] = *(const bf16x8*)(rb + 2 * ABYTES + aoff[i]);
#pragma unroll
      for (int j = 0; j < FJ; ++j) BX[j] = *(const bf16x8*)(rb + NP * ABYTES + 2 * BBYTES + boff[j]);
#pragma unroll
      for (int i = 0; i < FI; ++i)
#pragma unroll
        for (int j = 0; j < FJ; ++j) {
          acc2[i][j] = __builtin_amdgcn_mfma_f32_16x16x32_bf16(AH[i], BX[j], acc2[i][j], 0, 0, 0);
          acc2[i][j] = __builtin_amdgcn_mfma_f32_16x16x32_bf16(AX[i], BH[j], acc2[i][j], 0, 0, 0);
        }
    }
#pragma unroll
    for (int i = 0; i < FI; ++i) AX[i] = *(const bf16x8*)(rb + 1 * ABYTES + aoff[i]);
#pragma unroll
    for (int j = 0; j < FJ; ++j) BX[j] = *(const bf16x8*)(rb + NP * ABYTES + 1 * BBYTES + boff[j]);
#pragma unroll
    for (int i = 0; i < FI; ++i)
#pragma unroll
      for (int j = 0; j < FJ; ++j) {
        acc2[i][j] = __builtin_amdgcn_mfma_f32_16x16x32_bf16(AH[i], BX[j], acc2[i][j], 0, 0, 0);
        acc2[i][j] = __builtin_amdgcn_mfma_f32_16x16x32_bf16(AX[i], BH[j], acc2[i][j], 0, 0, 0);
        if constexpr (NPROD == 6)
          acc2[i][j] = __builtin_amdgcn_mfma_f32_16x16x32_bf16(AX[i], BX[j], acc2[i][j], 0, 0, 0);
      }
  };

  STAGE(0, 0);
  int cur = 0;
  for (int kt = 32; kt < K; kt += 32) {
    STAGE(cur ^ 1, kt);
    if constexpr (CALLS == 9) asm volatile("s_waitcnt vmcnt(9)" ::: "memory");
    else asm volatile("s_waitcnt vmcnt(6)" ::: "memory");
    __builtin_amdgcn_s_barrier();
    COMPUTE(smem + cur * HALF);
    asm volatile("s_waitcnt lgkmcnt(0)" ::: "memory");
    __builtin_amdgcn_s_barrier();
    cur ^= 1;
  }
  asm volatile("s_waitcnt vmcnt(0)" ::: "memory");
  __builtin_amdgcn_s_barrier();
  COMPUTE(smem + cur * HALF);

  const int fc = ln & 15;
  const int fr4 = (ln >> 4) << 2;
#pragma unroll
  for (int i = 0; i < FI; ++i) {
    const int rbase = m0 + wr * WM + i * 16 + fr4;
#pragma unroll
    for (int j = 0; j < FJ; ++j) {
      const int c = n0 + wc * WN + j * 16 + fc;
      const float bv = bias ? bias[c] : 0.0f;
#pragma unroll
      for (int q = 0; q < 4; ++q) {
        const float val = (acc1[i][j][q] + acc2[i][j][q]) * scale + bv;
        const long off = zC + (long)(rbase + q) * N + c;
        if constexpr (OUTMODE == 0) {
          C[off] = val;
        } else if constexpr (OUTMODE == 1) {
          const bf16 h = __float2bfloat16(val);
          const float r = val - __bfloat162float(h);
          const bf16 m = __float2bfloat16(r);
          Ch[off] = h; Cm[off] = m;
          Cl[off] = __float2bfloat16(r - __bfloat162float(m));
        } else {
          const bf16 h = __float2bfloat16(val);
          Ch[off] = h;
          Cm[off] = __float2bfloat16(val - __bfloat162float(h));
        }
      }
    }
  }
}

// ---------- radix-select top-64 + softmax + dense attn + out = p·VW + bo ----------
__device__ __forceinline__ unsigned f2key(float f) {
  const unsigned u = __float_as_uint(f);
  return (u & 0x80000000u) ? ~u : (u | 0x80000000u);
}

__global__ __launch_bounds__(256) void topk_av_kernel(
    const float* __restrict__ scores, const float* __restrict__ VW,
    const float* __restrict__ bo, float* __restrict__ attn, float* __restrict__ out) {
  const int row = blockIdx.x;  // 0..8191
  const int t = threadIdx.x, ln = t & 63, w = t >> 6;
  const float* srow = scores + (long)row * kS;

  __shared__ __align__(16) unsigned hist[2048];
  __shared__ float s_wval[kTopK];
  __shared__ int s_wcol[kTopK];
  __shared__ unsigned wsum[4];
  __shared__ int s_cut, s_ngt, s_nw, s_ntie;
  __shared__ int s_tie[128];
  __shared__ float s_tieval;

  if (t == 0) { s_nw = 0; s_ntie = 0; }

  float val[8]; unsigned key[8];
  {
    const float4 q0 = ((const float4*)srow)[t];
    const float4 q1 = ((const float4*)srow)[t + 256];
    val[0] = q0.x; val[1] = q0.y; val[2] = q0.z; val[3] = q0.w;
    val[4] = q1.x; val[5] = q1.y; val[6] = q1.z; val[7] = q1.w;
  }
#pragma unroll
  for (int j = 0; j < 8; ++j) key[j] = f2key(val[j]);

  unsigned alive = 0xFFu, winner = 0u;
  int rem = kTopK, done = 0;

  for (int level = 0; level < 3; ++level) {
    const int shift = (level == 0) ? 21 : (level == 1) ? 10 : 0;
    const unsigned bmask = (level == 2) ? 0x3FFu : 0x7FFu;
    for (int i = t; i < 2048; i += 256) hist[i] = 0u;
    __syncthreads();
#pragma unroll
    for (int j = 0; j < 8; ++j)
      if (alive & (1u << j)) atomicAdd(&hist[(key[j] >> shift) & bmask], 1u);
    __syncthreads();

    unsigned h[8]; unsigned ts = 0u;
#pragma unroll
    for (int b = 0; b < 8; ++b) { h[b] = hist[8 * t + b]; ts += h[b]; }
    unsigned ss = ts;
#pragma unroll
    for (int off = 1; off < 64; off <<= 1) {
      const unsigned o = __shfl_down(ss, off);
      if (ln + off < 64) ss += o;
    }
    if (ln == 0) wsum[w] = ss;
    __syncthreads();
    unsigned run = ss - ts;
    for (int u = w + 1; u < 4; ++u) run += wsum[u];
#pragma unroll
    for (int b = 7; b >= 0; --b) {
      if (run < (unsigned)rem && run + h[b] >= (unsigned)rem) {
        s_cut = 8 * t + b;
        s_ngt = (int)run;
      }
      run += h[b];
    }
    __syncthreads();
    const int cut = s_cut;
    const int ngt = s_ngt;
    const int incut = (int)hist[cut];
    rem -= ngt;
#pragma unroll
    for (int j = 0; j < 8; ++j) {
      if (!(alive & (1u << j))) continue;
      const int b = (int)((key[j] >> shift) & bmask);
      if (b > cut) { winner |= 1u << j; alive &= ~(1u << j); }
      else if (b < cut) alive &= ~(1u << j);
    }
    if (incut == rem) {
      winner |= alive; alive = 0u; done = 1;
    } else if (level == 2) {
#pragma unroll
      for (int j = 0; j < 8; ++j)
        if (alive & (1u << j)) {
          const int pos = atomicAdd(&s_ntie, 1);
          const int col = (j < 4) ? (4 * t + j) : (1024 + 4 * t + j - 4);
          if (pos < 128) s_tie[pos] = col;
          s_tieval = val[j];
        }
      __syncthreads();
      if (w == 0) {
        volatile int* vt = s_tie;
        const int n = (s_ntie < 128) ? s_ntie : 128;
        const int take = (rem < n) ? rem : n;
        for (int it = 0; it < take; ++it) {
          int c0 = (ln < n) ? vt[ln] : 0x7FFFFFFF;
          int c1 = (ln + 64 < n) ? vt[ln + 64] : 0x7FFFFFFF;
          int bc, bs;
          if (c1 < c0) { bc = c1; bs = ln + 64; } else { bc = c0; bs = ln; }
#pragma unroll
          for (int off = 32; off; off >>= 1) {
            const int oc = __shfl_xor(bc, off);
            const int os = __shfl_xor(bs, off);
            if (oc < bc) { bc = oc; bs = os; }
          }
          if (ln == 0) {
            vt[bs] = 0x7FFFFFFF;
            const int p = s_nw;
            s_wcol[p] = bc; s_wval[p] = s_tieval;
            s_nw = p + 1;
          }
        }
      }
      alive = 0u;
      done = 1;
    }
    __syncthreads();
    if (done) break;
  }

#pragma unroll
  for (int j = 0; j < 8; ++j)
    if (winner & (1u << j)) {
      const int pos = atomicAdd(&s_nw, 1);
      const int col = (j < 4) ? (4 * t + j) : (1024 + 4 * t + j - 4);
      if (pos < kTopK) { s_wcol[pos] = col; s_wval[pos] = val[j]; }
    }
  __syncthreads();

  if (w == 0) {
    const float v = s_wval[ln];
    float m = v;
#pragma unroll
    for (int off = 32; off; off >>= 1) m = fmaxf(m, __shfl_xor(m, off));
    float p = expf(v - m);
    float Z = p;
#pragma unroll
    for (int off = 32; off; off >>= 1) Z += __shfl_xor(Z, off);
    p /= Z;
    s_wval[ln] = p;
  }
  __syncthreads();

  // dense attn row
  float* lrow = (float*)hist;
  ((float4*)lrow)[t] = make_float4(0.f, 0.f, 0.f, 0.f);
  ((float4*)lrow)[t + 256] = make_float4(0.f, 0.f, 0.f, 0.f);
  __syncthreads();
  if (t < kTopK) lrow[s_wcol[t]] = s_wval[t];
  __syncthreads();
  float4* dst = (float4*)(attn + (long)row * kS);
  dst[t] = ((const float4*)lrow)[t];
  dst[t + 256] = ((const float4*)lrow)[t + 256];

  // out[row] = sum_j p_j * VW[b*2048 + col_j] + bo  (Wo pre-folded into VW)
  const int b = row >> 11;
  const float* VWb = VW + (long)b * kS * kD;
  const int c = t * 2;
  float ax = 0.f, ay = 0.f;
#pragma unroll 4
  for (int i = 0; i < kTopK; ++i) {
    const float2 vv = *(const float2*)(VWb + (long)s_wcol[i] * kD + c);
    const float p = s_wval[i];
    ax = fmaf(p, vv.x, ax);
    ay = fmaf(p, vv.y, ay);
  }
  const float2 bb = *(const float2*)(bo + c);
  float2 o2 = make_float2(ax + bb.x, ay + bb.y);
  *(float2*)(out + (long)row * kD + c) = o2;
}

extern "C" void kernel_launch(void* const* d_in, const int* in_sizes, int n_in,
                              void* d_out, int out_size, void* d_ws, size_t ws_size,
                              hipStream_t stream) {
  (void)in_sizes; (void)n_in; (void)out_size; (void)ws_size;
  const float* x = (const float*)d_in[0];
  const float* Wq = (const float*)d_in[1];
  const float* bq = (const float*)d_in[2];
  const float* Wk = (const float*)d_in[3];
  const float* bk = (const float*)d_in[4];
  const float* Wv = (const float*)d_in[5];
  const float* bv = (const float*)d_in[6];
  const float* Wo = (const float*)d_in[7];
  const float* bo = (const float*)d_in[8];

  float* out = (float*)d_out;             // [4,2048,512]
  float* attn = out + (long)kRows * kD;   // [4,2048,2048]

  const size_t SZ_ROWS = (size_t)kRows * kD * 2;  // 8 MB bf16 [8192,512]
  const size_t SZ_W = (size_t)kD * kD * 2;        // 512 KB bf16 [512,512]
  char* ws = (char*)d_ws;

  // region A (67.1 MB): x3 splits first, then scores overwrites (x3 dead by then)
  bf16* xh = (bf16*)(ws + 0);
  bf16* xm = (bf16*)(ws + SZ_ROWS);
  bf16* xl = (bf16*)(ws + 2 * SZ_ROWS);
  float* scores = (float*)(ws + 0);  // 67108864 B
  size_t off = 67108864;
  auto alloc = [&](size_t bytes) {
    void* p = ws + off;
    off += (bytes + 255) & ~(size_t)255;
    return p;
  };
  bf16* Wqh = (bf16*)alloc(SZ_W); bf16* Wqm = (bf16*)alloc(SZ_W); bf16* Wql = (bf16*)alloc(SZ_W);
  bf16* Wkh = (bf16*)alloc(SZ_W); bf16* Wkm = (bf16*)alloc(SZ_W); bf16* Wkl = (bf16*)alloc(SZ_W);
  bf16* Wvh = (bf16*)alloc(SZ_W); bf16* Wvm = (bf16*)alloc(SZ_W);
  bf16* Woh = (bf16*)alloc(SZ_W); bf16* Wom = (bf16*)alloc(SZ_W);
  bf16* Wvl = (bf16*)alloc(SZ_W); bf16* Wol = (bf16*)alloc(SZ_W);
  // region C (48 MB): Q3,K3 splits
  char* regC = (char*)alloc(6 * SZ_ROWS);
  bf16* Qh = (bf16*)(regC);
  bf16* Qm = (bf16*)(regC + SZ_ROWS);
  bf16* Ql = (bf16*)(regC + 2 * SZ_ROWS);
  bf16* Kh = (bf16*)(regC + 3 * SZ_ROWS);
  bf16* Km = (bf16*)(regC + 4 * SZ_ROWS);
  bf16* Kl = (bf16*)(regC + 5 * SZ_ROWS);
  // region D (16 MB): V h/m splits; region E (16.8 MB): VW fp32
  bf16* Vh = (bf16*)alloc(SZ_ROWS);
  bf16* Vm = (bf16*)alloc(SZ_ROWS);
  float* VW = (float*)alloc((size_t)kRows * kD * 4);

  const float inv_sqrt_d = 1.0f / sqrtf((float)kD);

  // 1. splits
  split3<<<2048, 256, 0, stream>>>(x, xh, xm, xl, kRows * kD);
  {
    WSplitArgs a;
    a.w[0] = Wq; a.w[1] = Wk; a.w[2] = Wv; a.w[3] = Wo;
    a.h[0] = Wqh; a.h[1] = Wkh; a.h[2] = Wvh; a.h[3] = Woh;
    a.m[0] = Wqm; a.m[1] = Wkm; a.m[2] = Wvm; a.m[3] = Wom;
    a.l[0] = Wql; a.l[1] = Wkl; a.l[2] = Wvl; a.l[3] = Wol;
    split3x4<<<dim3(128, 4), 256, 0, stream>>>(a, kD * kD);
  }

  const int LDS_P6 = 2 * 3 * (128 + 64) * 64;   // 73728
  const int LDS_P3 = 2 * 2 * (128 + 64) * 64;   // 49152
  const int LDS_S  = 2 * 3 * (256 + 128) * 64;  // 147456
  const dim3 gP(kD / 64, kRows / 128, 1);         // 512 blocks
  const dim3 gScore(kS / 128, kS / 256, kBatch);  // 512 blocks

  // 2. Q,K projections (6-product) -> h/m/l
  gemm_pipe<1, 6, 128, 64, 2, 2><<<gP, 256, LDS_P6, stream>>>(xh, xm, xl, Wqh, Wqm, Wql,
      nullptr, Qh, Qm, Ql, bq, 1.0f, kD, kD, 0, 0, 0);
  gemm_pipe<1, 6, 128, 64, 2, 2><<<gP, 256, LDS_P6, stream>>>(xh, xm, xl, Wkh, Wkm, Wkl,
      nullptr, Kh, Km, Kl, bk, 1.0f, kD, kD, 0, 0, 0);
  // 3. V projection (3-product) -> h/m splits (includes bv)
  gemm_pipe<2, 3, 128, 64, 2, 2><<<gP, 256, LDS_P3, stream>>>(xh, xm, nullptr, Wvh, Wvm, nullptr,
      nullptr, Vh, Vm, nullptr, bv, 1.0f, kD, kD, 0, 0, 0);
  // 4. VW = V @ Wo^T (3-product, no bias) -> fp32; out-projection pre-folded
  gemm_pipe<0, 3, 128, 64, 2, 2><<<gP, 256, LDS_P3, stream>>>(Vh, Vm, nullptr, Woh, Wom, nullptr,
      VW, nullptr, nullptr, nullptr, nullptr, 1.0f, kD, kD, 0, 0, 0);
  // 5. scores = (Q @ K^T) * inv_sqrt_d (round-5-proven schedule; overwrites region A)
  gemm_pipe<0, 6, 256, 128, 4, 2><<<gScore, 512, LDS_S, stream>>>(Qh, Qm, Ql, Kh, Km, Kl,
      scores, nullptr, nullptr, nullptr, nullptr, inv_sqrt_d, kS, kD,
      (long)kS * kD, (long)kS * kD, (long)kS * kS);
  // 6. top-64 + softmax + dense attn + out (VW gather, bo added here)
  topk_av_kernel<<<kRows, 256, 0, stream>>>(scores, VW, bo, attn, out);
}

// Round 8
// 251.863 us; speedup vs baseline: 3.5382x; 1.1256x over previous
//
#include <hip/hip_runtime.h>
#include <hip/hip_bf16.h>
#include <math.h>

#define AS1 __attribute__((address_space(1)))
#define AS3 __attribute__((address_space(3)))

typedef __attribute__((ext_vector_type(8))) short bf16x8;
typedef __attribute__((ext_vector_type(4))) float f32x4;
typedef __hip_bfloat16 bf16;

namespace {
constexpr int kBatch = 4, kS = 2048, kD = 512;
constexpr int kRows = kBatch * kS;   // 8192
constexpr int kTopK = 64;
constexpr int kSel = 65;             // select 65, refine the 64/65 boundary
}

__device__ __forceinline__ void async16(void* lds, const void* g) {
  __builtin_amdgcn_global_load_lds((AS1 void*)g, (AS3 void*)lds, 16, 0, 0);
}

// ---------- fp32 -> bf16 h/m/l 3-way split ----------
__global__ __launch_bounds__(256) void split3(
    const float* __restrict__ in, bf16* __restrict__ h, bf16* __restrict__ m,
    bf16* __restrict__ l, int n) {
  int i = blockIdx.x * 256 + threadIdx.x;
  const int stride = gridDim.x * 256;
  for (; i < n; i += stride) {
    const float x = in[i];
    const bf16 hh = __float2bfloat16(x);
    const float r = x - __bfloat162float(hh);
    const bf16 mm = __float2bfloat16(r);
    const float r2 = r - __bfloat162float(mm);
    h[i] = hh; m[i] = mm; l[i] = __float2bfloat16(r2);
  }
}

struct WSplitArgs {
  const float* w[4];
  bf16* h[4]; bf16* m[4]; bf16* l[4];
};
__global__ __launch_bounds__(256) void split3x4(WSplitArgs a, int n) {
  const int g = blockIdx.y;
  const float* in = a.w[g];
  bf16* h = a.h[g]; bf16* m = a.m[g]; bf16* l = a.l[g];
  int i = blockIdx.x * 256 + threadIdx.x;
  const int stride = gridDim.x * 256;
  for (; i < n; i += stride) {
    const float x = in[i];
    const bf16 hh = __float2bfloat16(x);
    const float r = x - __bfloat162float(hh);
    const bf16 mm = __float2bfloat16(r);
    const float r2 = r - __bfloat162float(mm);
    h[i] = hh; m[i] = mm; l[i] = __float2bfloat16(r2);
  }
}

// ---------- pipelined C[M,N] = scale*(A @ B^T) + bias, split-bf16 precision ----------
// PROVEN structure (rounds 5 & 7, passed post-timing): dbuf LDS + counted vmcnt,
// one STAGE + one monolithic COMPUTE per K-step, two raw barriers.
template<int OUTMODE, int NPROD, int BM, int BN, int WAVES_M, int WAVES_N>
__global__ __launch_bounds__(64 * WAVES_M * WAVES_N, 2) void gemm_pipe(
    const bf16* __restrict__ Ah, const bf16* __restrict__ Am, const bf16* __restrict__ Al,
    const bf16* __restrict__ Bh, const bf16* __restrict__ Bm, const bf16* __restrict__ Bl,
    float* __restrict__ C, bf16* __restrict__ Ch, bf16* __restrict__ Cm, bf16* __restrict__ Cl,
    const float* __restrict__ bias, float scale, int N, int K,
    long batchA, long batchB, long batchC) {
  constexpr int NP = (NPROD == 6) ? 3 : 2;
  constexpr int T = 64 * WAVES_M * WAVES_N;
  constexpr int WM = BM / WAVES_M, WN = BN / WAVES_N;
  constexpr int FI = WM / 16, FJ = WN / 16;
  constexpr int ABYTES = BM * 64, BBYTES = BN * 64;
  constexpr int HALF = NP * (ABYTES + BBYTES);
  constexpr int SPAN = T * 16;
  constexpr int CALLS = HALF / SPAN;
  static_assert(HALF % SPAN == 0, "staging must be whole call-spans");
  extern __shared__ char smem[];

  const int t = threadIdx.x;
  const int wi = t >> 6, ln = t & 63;
  const int wr = wi / WAVES_N, wc = wi % WAVES_N;

  int bx, by, bz;
  {
    const int F = blockIdx.x + gridDim.x * (blockIdx.y + gridDim.y * blockIdx.z);
    const int cpx = (gridDim.x * gridDim.y * gridDim.z) >> 3;
    const int L = (F & 7) * cpx + (F >> 3);
    bx = L % gridDim.x;
    const int r = L / gridDim.x;
    by = r % gridDim.y; bz = r / gridDim.y;
  }
  const int m0 = by * BM, n0 = bx * BN;
  const long zA = (long)bz * batchA;
  const long zB = (long)bz * batchB;
  const long zC = (long)bz * batchC;

  const bf16* gp[CALLS];
#pragma unroll
  for (int q = 0; q < CALLS; ++q) {
    const int o = q * SPAN + t * 16;
    const bf16* base; long rbase; int local;
    if (o < NP * ABYTES) {
      const int p = o / ABYTES; local = o % ABYTES;
      base = (p == 0) ? Ah : (p == 1) ? Am : Al;
      rbase = zA + (long)m0 * K;
    } else {
      const int o2 = o - NP * ABYTES;
      const int p = o2 / BBYTES; local = o2 % BBYTES;
      base = (p == 0) ? Bh : (p == 1) ? Bm : Bl;
      rbase = zB + (long)n0 * K;
    }
    const int s = local >> 7;
    const int pc = (local >> 4) & 7;
    const int lc = pc ^ (s & 7);
    const int row = 2 * s + (lc >> 2);
    const int ke = (lc & 3) << 3;
    gp[q] = base + rbase + (long)row * K + ke;
  }
  const int lofs = wi * 1024;

  const int fr = ln & 15, cc = ln >> 4;
  const int c2 = ((fr & 1) << 2) | cc;
  int aoff[FI], boff[FJ];
#pragma unroll
  for (int i = 0; i < FI; ++i) {
    const int s = (wr * WM + i * 16 + fr) >> 1;
    aoff[i] = s * 128 + ((c2 ^ (s & 7)) << 4);
  }
#pragma unroll
  for (int j = 0; j < FJ; ++j) {
    const int s = (wc * WN + j * 16 + fr) >> 1;
    boff[j] = s * 128 + ((c2 ^ (s & 7)) << 4);
  }

  f32x4 acc1[FI][FJ] = {}, acc2[FI][FJ] = {};

  auto STAGE = [&](int buf, int kt) {
#pragma unroll
    for (int q = 0; q < CALLS; ++q)
      async16(smem + buf * HALF + q * SPAN + lofs, gp[q] + kt);
  };

  auto COMPUTE = [&](const char* rb) {
    bf16x8 AH[FI], BH[FJ], AX[FI], BX[FJ];
#pragma unroll
    for (int i = 0; i < FI; ++i) AH[i] = *(const bf16x8*)(rb + aoff[i]);
#pragma unroll
    for (int j = 0; j < FJ; ++j) BH[j] = *(const bf16x8*)(rb + NP * ABYTES + boff[j]);
#pragma unroll
    for (int i = 0; i < FI; ++i)
#pragma unroll
      for (int j = 0; j < FJ; ++j)
        acc1[i][j] = __builtin_amdgcn_mfma_f32_16x16x32_bf16(AH[i], BH[j], acc1[i][j], 0, 0, 0);
    if constexpr (NPROD == 6) {
#pragma unroll
      for (int i = 0; i < FI; ++i) AX[i] = *(const bf16x8*)(rb + 2 * ABYTES + aoff[i]);
#pragma unroll
      for (int j = 0; j < FJ; ++j) BX[j] = *(const bf16x8*)(rb + NP * ABYTES + 2 * BBYTES + boff[j]);
#pragma unroll
      for (int i = 0; i < FI; ++i)
#pragma unroll
        for (int j = 0; j < FJ; ++j) {
          acc2[i][j] = __builtin_amdgcn_mfma_f32_16x16x32_bf16(AH[i], BX[j], acc2[i][j], 0, 0, 0);
          acc2[i][j] = __builtin_amdgcn_mfma_f32_16x16x32_bf16(AX[i], BH[j], acc2[i][j], 0, 0, 0);
        }
    }
#pragma unroll
    for (int i = 0; i < FI; ++i) AX[i] = *(const bf16x8*)(rb + 1 * ABYTES + aoff[i]);
#pragma unroll
    for (int j = 0; j < FJ; ++j) BX[j] = *(const bf16x8*)(rb + NP * ABYTES + 1 * BBYTES + boff[j]);
#pragma unroll
    for (int i = 0; i < FI; ++i)
#pragma unroll
      for (int j = 0; j < FJ; ++j) {
        acc2[i][j] = __builtin_amdgcn_mfma_f32_16x16x32_bf16(AH[i], BX[j], acc2[i][j], 0, 0, 0);
        acc2[i][j] = __builtin_amdgcn_mfma_f32_16x16x32_bf16(AX[i], BH[j], acc2[i][j], 0, 0, 0);
        if constexpr (NPROD == 6)
          acc2[i][j] = __builtin_amdgcn_mfma_f32_16x16x32_bf16(AX[i], BX[j], acc2[i][j], 0, 0, 0);
      }
  };

  STAGE(0, 0);
  int cur = 0;
  for (int kt = 32; kt < K; kt += 32) {
    STAGE(cur ^ 1, kt);
    if constexpr (CALLS == 9) asm volatile("s_waitcnt vmcnt(9)" ::: "memory");
    else asm volatile("s_waitcnt vmcnt(6)" ::: "memory");
    __builtin_amdgcn_s_barrier();
    COMPUTE(smem + cur * HALF);
    asm volatile("s_waitcnt lgkmcnt(0)" ::: "memory");
    __builtin_amdgcn_s_barrier();
    cur ^= 1;
  }
  asm volatile("s_waitcnt vmcnt(0)" ::: "memory");
  __builtin_amdgcn_s_barrier();
  COMPUTE(smem + cur * HALF);

  const int fc = ln & 15;
  const int fr4 = (ln >> 4) << 2;
#pragma unroll
  for (int i = 0; i < FI; ++i) {
    const int rbase = m0 + wr * WM + i * 16 + fr4;
#pragma unroll
    for (int j = 0; j < FJ; ++j) {
      const int c = n0 + wc * WN + j * 16 + fc;
      const float bv = bias ? bias[c] : 0.0f;
#pragma unroll
      for (int q = 0; q < 4; ++q) {
        const float val = (acc1[i][j][q] + acc2[i][j][q]) * scale + bv;
        const long off = zC + (long)(rbase + q) * N + c;
        if constexpr (OUTMODE == 0) {
          C[off] = val;
        } else if constexpr (OUTMODE == 1) {
          const bf16 h = __float2bfloat16(val);
          const float r = val - __bfloat162float(h);
          const bf16 m = __float2bfloat16(r);
          Ch[off] = h; Cm[off] = m;
          Cl[off] = __float2bfloat16(r - __bfloat162float(m));
        } else {
          const bf16 h = __float2bfloat16(val);
          Ch[off] = h;
          Cm[off] = __float2bfloat16(val - __bfloat162float(h));
        }
      }
    }
  }
}

// ---------- radix-select top-65 + fp64 boundary refine + softmax + attn + out ----------
__device__ __forceinline__ unsigned f2key(float f) {
  const unsigned u = __float_as_uint(f);
  return (u & 0x80000000u) ? ~u : (u | 0x80000000u);
}
// "a worse than b" for exclusion (lower value, tie -> larger col excluded first)
__device__ __forceinline__ bool worse(float av, int ac, float bv, int bc) {
  return (av < bv) || (av == bv && ac > bc);
}

__global__ __launch_bounds__(256) void topk_av_kernel(
    const float* __restrict__ scores, const float* __restrict__ VW,
    const float* __restrict__ bo,
    const bf16* __restrict__ Qh, const bf16* __restrict__ Qm, const bf16* __restrict__ Ql,
    const bf16* __restrict__ Kh, const bf16* __restrict__ Km, const bf16* __restrict__ Kl,
    float* __restrict__ attn, float* __restrict__ out) {
  const int row = blockIdx.x;  // 0..8191
  const int t = threadIdx.x, ln = t & 63, w = t >> 6;
  const float* srow = scores + (long)row * kS;

  __shared__ __align__(16) unsigned hist[2048];
  __shared__ float s_wval[kSel];
  __shared__ int s_wcol[kSel];
  __shared__ float s_kv[kTopK];
  __shared__ int s_kc[kTopK];
  __shared__ unsigned wsum[4];
  __shared__ int s_cut, s_ngt, s_nw, s_ntie;
  __shared__ int s_tie[128];
  __shared__ float s_tieval;
  __shared__ int s_c0, s_c1, s_excl, s_slot;
  __shared__ float s_gap;
  __shared__ double rd0[4], rd1[4];

  if (t == 0) { s_nw = 0; s_ntie = 0; }

  float val[8]; unsigned key[8];
  {
    const float4 q0 = ((const float4*)srow)[t];
    const float4 q1 = ((const float4*)srow)[t + 256];
    val[0] = q0.x; val[1] = q0.y; val[2] = q0.z; val[3] = q0.w;
    val[4] = q1.x; val[5] = q1.y; val[6] = q1.z; val[7] = q1.w;
  }
#pragma unroll
  for (int j = 0; j < 8; ++j) key[j] = f2key(val[j]);

  unsigned alive = 0xFFu, winner = 0u;
  int rem = kSel, done = 0;

  for (int level = 0; level < 3; ++level) {
    const int shift = (level == 0) ? 21 : (level == 1) ? 10 : 0;
    const unsigned bmask = (level == 2) ? 0x3FFu : 0x7FFu;
    for (int i = t; i < 2048; i += 256) hist[i] = 0u;
    __syncthreads();
#pragma unroll
    for (int j = 0; j < 8; ++j)
      if (alive & (1u << j)) atomicAdd(&hist[(key[j] >> shift) & bmask], 1u);
    __syncthreads();

    unsigned h[8]; unsigned ts = 0u;
#pragma unroll
    for (int b = 0; b < 8; ++b) { h[b] = hist[8 * t + b]; ts += h[b]; }
    unsigned ss = ts;
#pragma unroll
    for (int off = 1; off < 64; off <<= 1) {
      const unsigned o = __shfl_down(ss, off);
      if (ln + off < 64) ss += o;
    }
    if (ln == 0) wsum[w] = ss;
    __syncthreads();
    unsigned run = ss - ts;
    for (int u = w + 1; u < 4; ++u) run += wsum[u];
#pragma unroll
    for (int b = 7; b >= 0; --b) {
      if (run < (unsigned)rem && run + h[b] >= (unsigned)rem) {
        s_cut = 8 * t + b;
        s_ngt = (int)run;
      }
      run += h[b];
    }
    __syncthreads();
    const int cut = s_cut;
    const int ngt = s_ngt;
    const int incut = (int)hist[cut];
    rem -= ngt;
#pragma unroll
    for (int j = 0; j < 8; ++j) {
      if (!(alive & (1u << j))) continue;
      const int b = (int)((key[j] >> shift) & bmask);
      if (b > cut) { winner |= 1u << j; alive &= ~(1u << j); }
      else if (b < cut) alive &= ~(1u << j);
    }
    if (incut == rem) {
      winner |= alive; alive = 0u; done = 1;
    } else if (level == 2) {
#pragma unroll
      for (int j = 0; j < 8; ++j)
        if (alive & (1u << j)) {
          const int pos = atomicAdd(&s_ntie, 1);
          const int col = (j < 4) ? (4 * t + j) : (1024 + 4 * t + j - 4);
          if (pos < 128) s_tie[pos] = col;
          s_tieval = val[j];
        }
      __syncthreads();
      if (w == 0) {
        volatile int* vt = s_tie;
        const int n = (s_ntie < 128) ? s_ntie : 128;
        const int take = (rem < n) ? rem : n;
        for (int it = 0; it < take; ++it) {
          int c0 = (ln < n) ? vt[ln] : 0x7FFFFFFF;
          int c1 = (ln + 64 < n) ? vt[ln + 64] : 0x7FFFFFFF;
          int bc, bs;
          if (c1 < c0) { bc = c1; bs = ln + 64; } else { bc = c0; bs = ln; }
#pragma unroll
          for (int off = 32; off; off >>= 1) {
            const int oc = __shfl_xor(bc, off);
            const int os = __shfl_xor(bs, off);
            if (oc < bc) { bc = oc; bs = os; }
          }
          if (ln == 0) {
            vt[bs] = 0x7FFFFFFF;
            const int p = s_nw;
            s_wcol[p] = bc; s_wval[p] = s_tieval;
            s_nw = p + 1;
          }
        }
      }
      alive = 0u;
      done = 1;
    }
    __syncthreads();
    if (done) break;
  }

#pragma unroll
  for (int j = 0; j < 8; ++j)
    if (winner & (1u << j)) {
      const int pos = atomicAdd(&s_nw, 1);
      const int col = (j < 4) ? (4 * t + j) : (1024 + 4 * t + j - 4);
      if (pos < kSel) { s_wcol[pos] = col; s_wval[pos] = val[j]; }
    }
  __syncthreads();

  // ---- find worst & second-worst among the 65 (wave 0) ----
  if (w == 0) {
    float wv = s_wval[ln]; int wc2 = s_wcol[ln];
    float sv = 1e30f; int sc = -1;
    if (ln == 0) {  // fold entry 64 into lane 0's pair
      const float v64 = s_wval[64]; const int c64 = s_wcol[64];
      if (worse(v64, c64, wv, wc2)) { sv = wv; sc = wc2; wv = v64; wc2 = c64; }
      else { sv = v64; sc = c64; }
    }
#pragma unroll
    for (int off = 32; off; off >>= 1) {
      const float owv = __shfl_down(wv, off); const int owc = __shfl_down(wc2, off);
      const float osv = __shfl_down(sv, off); const int osc = __shfl_down(sc, off);
      if (worse(owv, owc, wv, wc2)) {
        // other's worst becomes worst; second = worse of (own worst, other's second)
        const bool x = worse(wv, wc2, osv, osc);
        sv = x ? wv : osv; sc = x ? wc2 : osc;
        wv = owv; wc2 = owc;
      } else {
        const bool x = worse(owv, owc, sv, sc);
        sv = x ? owv : sv; sc = x ? owc : sc;
      }
    }
    if (ln == 0) {
      s_c0 = wc2; s_c1 = sc; s_gap = sv - wv;
      s_excl = wc2;  // default: exclude the approx-worst
    }
  }
  __syncthreads();

  // ---- fp64 boundary refine when the 64/65 approx gap is ambiguous ----
  if (s_nw == kSel && s_gap < 3e-4f) {
    const int b = row >> 11;
    const int cw = s_c0, cs = s_c1;
    const long qoff = (long)row * kD;
    const long k0off = ((long)(b << 11) + cw) * kD;
    const long k1off = ((long)(b << 11) + cs) * kD;
    double p0 = 0.0, p1 = 0.0;
    // each thread handles elements 2t, 2t+1 (packed bf16 pair loads)
    const unsigned qhp = ((const unsigned*)(Qh + qoff))[t];
    const unsigned qmp = ((const unsigned*)(Qm + qoff))[t];
    const unsigned qlp = ((const unsigned*)(Ql + qoff))[t];
    const unsigned k0h = ((const unsigned*)(Kh + k0off))[t];
    const unsigned k0m = ((const unsigned*)(Km + k0off))[t];
    const unsigned k0l = ((const unsigned*)(Kl + k0off))[t];
    const unsigned k1h = ((const unsigned*)(Kh + k1off))[t];
    const unsigned k1m = ((const unsigned*)(Km + k1off))[t];
    const unsigned k1l = ((const unsigned*)(Kl + k1off))[t];
    auto bflo = [](unsigned u) { return __uint_as_float(u << 16); };
    auto bfhi = [](unsigned u) { return __uint_as_float(u & 0xFFFF0000u); };
    {
      const double q0 = (double)bflo(qhp) + (double)bflo(qmp) + (double)bflo(qlp);
      const double q1 = (double)bfhi(qhp) + (double)bfhi(qmp) + (double)bfhi(qlp);
      const double a0 = (double)bflo(k0h) + (double)bflo(k0m) + (double)bflo(k0l);
      const double a1 = (double)bfhi(k0h) + (double)bfhi(k0m) + (double)bfhi(k0l);
      const double b0 = (double)bflo(k1h) + (double)bflo(k1m) + (double)bflo(k1l);
      const double b1 = (double)bfhi(k1h) + (double)bfhi(k1m) + (double)bfhi(k1l);
      p0 = q0 * a0 + q1 * a1;
      p1 = q0 * b0 + q1 * b1;
    }
#pragma unroll
    for (int off = 32; off; off >>= 1) {
      p0 += __shfl_down(p0, off);
      p1 += __shfl_down(p1, off);
    }
    if (ln == 0) { rd0[w] = p0; rd1[w] = p1; }
    __syncthreads();
    if (t == 0) {
      const double e0 = rd0[0] + rd0[1] + rd0[2] + rd0[3];  // exact score of cw
      const double e1 = rd1[0] + rd1[1] + rd1[2] + rd1[3];  // exact score of cs
      // keep the better; tie -> keep smaller col (exclude larger)
      if (e0 > e1 || (e0 == e1 && cw < cs)) s_excl = cs; else s_excl = cw;
    }
    __syncthreads();
  }

  // locate excluded slot and compact to 64 kept entries
  if (t == 0) s_slot = kSel - 1;
  __syncthreads();
  if (t < kSel && s_wcol[t] == s_excl) s_slot = t;
  __syncthreads();
  if (t < kTopK) {
    const int src = t + (t >= s_slot ? 1 : 0);
    s_kc[t] = s_wcol[src];
    s_kv[t] = s_wval[src];
  }
  __syncthreads();

  // softmax over kept 64 (wave 0)
  if (w == 0) {
    const float v = s_kv[ln];
    float m = v;
#pragma unroll
    for (int off = 32; off; off >>= 1) m = fmaxf(m, __shfl_xor(m, off));
    float p = expf(v - m);
    float Z = p;
#pragma unroll
    for (int off = 32; off; off >>= 1) Z += __shfl_xor(Z, off);
    p /= Z;
    s_kv[ln] = p;
  }
  __syncthreads();

  // dense attn row
  float* lrow = (float*)hist;
  ((float4*)lrow)[t] = make_float4(0.f, 0.f, 0.f, 0.f);
  ((float4*)lrow)[t + 256] = make_float4(0.f, 0.f, 0.f, 0.f);
  __syncthreads();
  if (t < kTopK) lrow[s_kc[t]] = s_kv[t];
  __syncthreads();
  float4* dst = (float4*)(attn + (long)row * kS);
  dst[t] = ((const float4*)lrow)[t];
  dst[t + 256] = ((const float4*)lrow)[t + 256];

  // out[row] = sum_j p_j * VW[b*2048 + col_j] + bo  (Wo pre-folded into VW)
  const int b = row >> 11;
  const float* VWb = VW + (long)b * kS * kD;
  const int c = t * 2;
  float ax = 0.f, ay = 0.f;
#pragma unroll 4
  for (int i = 0; i < kTopK; ++i) {
    const float2 vv = *(const float2*)(VWb + (long)s_kc[i] * kD + c);
    const float p = s_kv[i];
    ax = fmaf(p, vv.x, ax);
    ay = fmaf(p, vv.y, ay);
  }
  const float2 bb = *(const float2*)(bo + c);
  float2 o2 = make_float2(ax + bb.x, ay + bb.y);
  *(float2*)(out + (long)row * kD + c) = o2;
}

extern "C" void kernel_launch(void* const* d_in, const int* in_sizes, int n_in,
                              void* d_out, int out_size, void* d_ws, size_t ws_size,
                              hipStream_t stream) {
  (void)in_sizes; (void)n_in; (void)out_size; (void)ws_size;
  const float* x = (const float*)d_in[0];
  const float* Wq = (const float*)d_in[1];
  const float* bq = (const float*)d_in[2];
  const float* Wk = (const float*)d_in[3];
  const float* bk = (const float*)d_in[4];
  const float* Wv = (const float*)d_in[5];
  const float* bv = (const float*)d_in[6];
  const float* Wo = (const float*)d_in[7];
  const float* bo = (const float*)d_in[8];

  float* out = (float*)d_out;             // [4,2048,512]
  float* attn = out + (long)kRows * kD;   // [4,2048,2048]

  const size_t SZ_ROWS = (size_t)kRows * kD * 2;  // 8 MB bf16 [8192,512]
  const size_t SZ_W = (size_t)kD * kD * 2;        // 512 KB bf16 [512,512]
  char* ws = (char*)d_ws;

  // region A (67.1 MB): x3 splits first, then scores overwrites (x3 dead by then)
  bf16* xh = (bf16*)(ws + 0);
  bf16* xm = (bf16*)(ws + SZ_ROWS);
  bf16* xl = (bf16*)(ws + 2 * SZ_ROWS);
  float* scores = (float*)(ws + 0);  // 67108864 B
  size_t off = 67108864;
  auto alloc = [&](size_t bytes) {
    void* p = ws + off;
    off += (bytes + 255) & ~(size_t)255;
    return p;
  };
  bf16* Wqh = (bf16*)alloc(SZ_W); bf16* Wqm = (bf16*)alloc(SZ_W); bf16* Wql = (bf16*)alloc(SZ_W);
  bf16* Wkh = (bf16*)alloc(SZ_W); bf16* Wkm = (bf16*)alloc(SZ_W); bf16* Wkl = (bf16*)alloc(SZ_W);
  bf16* Wvh = (bf16*)alloc(SZ_W); bf16* Wvm = (bf16*)alloc(SZ_W);
  bf16* Woh = (bf16*)alloc(SZ_W); bf16* Wom = (bf16*)alloc(SZ_W);
  bf16* Wvl = (bf16*)alloc(SZ_W); bf16* Wol = (bf16*)alloc(SZ_W);
  // region C (48 MB): Q3,K3 splits (stay live through topk_av for the refine)
  char* regC = (char*)alloc(6 * SZ_ROWS);
  bf16* Qh = (bf16*)(regC);
  bf16* Qm = (bf16*)(regC + SZ_ROWS);
  bf16* Ql = (bf16*)(regC + 2 * SZ_ROWS);
  bf16* Kh = (bf16*)(regC + 3 * SZ_ROWS);
  bf16* Km = (bf16*)(regC + 4 * SZ_ROWS);
  bf16* Kl = (bf16*)(regC + 5 * SZ_ROWS);
  // region D (16 MB): V h/m splits; region E (16.8 MB): VW fp32
  bf16* Vh = (bf16*)alloc(SZ_ROWS);
  bf16* Vm = (bf16*)alloc(SZ_ROWS);
  float* VW = (float*)alloc((size_t)kRows * kD * 4);

  const float inv_sqrt_d = 1.0f / sqrtf((float)kD);

  // 1. splits
  split3<<<2048, 256, 0, stream>>>(x, xh, xm, xl, kRows * kD);
  {
    WSplitArgs a;
    a.w[0] = Wq; a.w[1] = Wk; a.w[2] = Wv; a.w[3] = Wo;
    a.h[0] = Wqh; a.h[1] = Wkh; a.h[2] = Wvh; a.h[3] = Woh;
    a.m[0] = Wqm; a.m[1] = Wkm; a.m[2] = Wvm; a.m[3] = Wom;
    a.l[0] = Wql; a.l[1] = Wkl; a.l[2] = Wvl; a.l[3] = Wol;
    split3x4<<<dim3(128, 4), 256, 0, stream>>>(a, kD * kD);
  }

  const int LDS_P6 = 2 * 3 * (128 + 64) * 64;   // 73728
  const int LDS_P3 = 2 * 2 * (128 + 64) * 64;   // 49152
  const int LDS_S3 = 2 * 2 * (256 + 128) * 64;  // 98304 (scores, 3-product)
  const dim3 gP(kD / 64, kRows / 128, 1);         // 512 blocks
  const dim3 gScore(kS / 128, kS / 256, kBatch);  // 512 blocks

  // 2. Q,K projections (6-product) -> h/m/l (l feeds the fp64 refine)
  gemm_pipe<1, 6, 128, 64, 2, 2><<<gP, 256, LDS_P6, stream>>>(xh, xm, xl, Wqh, Wqm, Wql,
      nullptr, Qh, Qm, Ql, bq, 1.0f, kD, kD, 0, 0, 0);
  gemm_pipe<1, 6, 128, 64, 2, 2><<<gP, 256, LDS_P6, stream>>>(xh, xm, xl, Wkh, Wkm, Wkl,
      nullptr, Kh, Km, Kl, bk, 1.0f, kD, kD, 0, 0, 0);
  // 3. V projection (3-product) -> h/m splits (includes bv)
  gemm_pipe<2, 3, 128, 64, 2, 2><<<gP, 256, LDS_P3, stream>>>(xh, xm, nullptr, Wvh, Wvm, nullptr,
      nullptr, Vh, Vm, nullptr, bv, 1.0f, kD, kD, 0, 0, 0);
  // 4. VW = V @ Wo^T (3-product) -> fp32; out-projection pre-folded
  gemm_pipe<0, 3, 128, 64, 2, 2><<<gP, 256, LDS_P3, stream>>>(Vh, Vm, nullptr, Woh, Wom, nullptr,
      VW, nullptr, nullptr, nullptr, nullptr, 1.0f, kD, kD, 0, 0, 0);
  // 5. scores = (Q @ K^T) * inv_sqrt_d — 3-product approx (boundary refined later)
  gemm_pipe<0, 3, 256, 128, 4, 2><<<gScore, 512, LDS_S3, stream>>>(Qh, Qm, nullptr, Kh, Km, nullptr,
      scores, nullptr, nullptr, nullptr, nullptr, inv_sqrt_d, kS, kD,
      (long)kS * kD, (long)kS * kD, (long)kS * kS);
  // 6. top-65 select + fp64 boundary refine + softmax + dense attn + out
  topk_av_kernel<<<kRows, 256, 0, stream>>>(scores, VW, bo, Qh, Qm, Ql, Kh, Km, Kl,
                                            attn, out);
}

// Round 9
// 246.281 us; speedup vs baseline: 3.6184x; 1.0227x over previous
//
#include <hip/hip_runtime.h>
#include <hip/hip_bf16.h>
#include <math.h>

#define AS1 __attribute__((address_space(1)))
#define AS3 __attribute__((address_space(3)))

typedef __attribute__((ext_vector_type(8))) short bf16x8;
typedef __attribute__((ext_vector_type(4))) float f32x4;
typedef __hip_bfloat16 bf16;

namespace {
constexpr int kBatch = 4, kS = 2048, kD = 512;
constexpr int kRows = kBatch * kS;   // 8192
constexpr int kTopK = 64;
constexpr int kSel = 65;             // select 65, refine the 64/65 boundary
}

__device__ __forceinline__ void async16(void* lds, const void* g) {
  __builtin_amdgcn_global_load_lds((AS1 void*)g, (AS3 void*)lds, 16, 0, 0);
}

template<int N> __device__ __forceinline__ void wait_vm() {
  if constexpr (N == 0) asm volatile("s_waitcnt vmcnt(0)" ::: "memory");
  else if constexpr (N == 3) asm volatile("s_waitcnt vmcnt(3)" ::: "memory");
  else if constexpr (N == 6) asm volatile("s_waitcnt vmcnt(6)" ::: "memory");
  else if constexpr (N == 9) asm volatile("s_waitcnt vmcnt(9)" ::: "memory");
  else static_assert(N == 0 || N == 3 || N == 6 || N == 9, "unsupported vmcnt");
}

// ---------- fp32 -> bf16 h/m/l 3-way split ----------
__global__ __launch_bounds__(256) void split3(
    const float* __restrict__ in, bf16* __restrict__ h, bf16* __restrict__ m,
    bf16* __restrict__ l, int n) {
  int i = blockIdx.x * 256 + threadIdx.x;
  const int stride = gridDim.x * 256;
  for (; i < n; i += stride) {
    const float x = in[i];
    const bf16 hh = __float2bfloat16(x);
    const float r = x - __bfloat162float(hh);
    const bf16 mm = __float2bfloat16(r);
    const float r2 = r - __bfloat162float(mm);
    h[i] = hh; m[i] = mm; l[i] = __float2bfloat16(r2);
  }
}

struct WSplitArgs {
  const float* w[4];
  bf16* h[4]; bf16* m[4]; bf16* l[4];
};
__global__ __launch_bounds__(256) void split3x4(WSplitArgs a, int n) {
  const int g = blockIdx.y;
  const float* in = a.w[g];
  bf16* h = a.h[g]; bf16* m = a.m[g]; bf16* l = a.l[g];
  int i = blockIdx.x * 256 + threadIdx.x;
  const int stride = gridDim.x * 256;
  for (; i < n; i += stride) {
    const float x = in[i];
    const bf16 hh = __float2bfloat16(x);
    const float r = x - __bfloat162float(hh);
    const bf16 mm = __float2bfloat16(r);
    const float r2 = r - __bfloat162float(mm);
    h[i] = hh; m[i] = mm; l[i] = __float2bfloat16(r2);
  }
}

// ---------- pipelined C[M,N] = scale*(A @ B^T) + bias, split-bf16 precision ----------
// PROVEN structure (rounds 5/7/8, passed post-timing): dbuf LDS + counted vmcnt,
// one STAGE + one monolithic COMPUTE per K-step, two raw barriers. The vmcnt
// invariant is generic in CALLS: at the wait, outstanding = 2*CALLS; waiting to
// CALLS means the previous tile fully landed while the next stays in flight.
// OUTMODE 0: fp32 C; 1: h/m/l out; 2: h/m out; 3: h out.
// NPROD 6: hh + (hl+lh) + (hm+mh+mm); 3: hh + (hm+mh); 1: hh only.
template<int OUTMODE, int NPROD, int BM, int BN, int WAVES_M, int WAVES_N>
__global__ __launch_bounds__(64 * WAVES_M * WAVES_N, 2) void gemm_pipe(
    const bf16* __restrict__ Ah, const bf16* __restrict__ Am, const bf16* __restrict__ Al,
    const bf16* __restrict__ Bh, const bf16* __restrict__ Bm, const bf16* __restrict__ Bl,
    float* __restrict__ C, bf16* __restrict__ Ch, bf16* __restrict__ Cm, bf16* __restrict__ Cl,
    const float* __restrict__ bias, float scale, int N, int K,
    long batchA, long batchB, long batchC) {
  constexpr int NP = (NPROD == 6) ? 3 : (NPROD == 3) ? 2 : 1;
  constexpr int T = 64 * WAVES_M * WAVES_N;
  constexpr int WM = BM / WAVES_M, WN = BN / WAVES_N;
  constexpr int FI = WM / 16, FJ = WN / 16;
  constexpr int ABYTES = BM * 64, BBYTES = BN * 64;
  constexpr int HALF = NP * (ABYTES + BBYTES);
  constexpr int SPAN = T * 16;
  constexpr int CALLS = HALF / SPAN;
  static_assert(HALF % SPAN == 0, "staging must be whole call-spans");
  extern __shared__ char smem[];

  const int t = threadIdx.x;
  const int wi = t >> 6, ln = t & 63;
  const int wr = wi / WAVES_N, wc = wi % WAVES_N;

  int bx, by, bz;
  {
    const int F = blockIdx.x + gridDim.x * (blockIdx.y + gridDim.y * blockIdx.z);
    const int cpx = (gridDim.x * gridDim.y * gridDim.z) >> 3;
    const int L = (F & 7) * cpx + (F >> 3);
    bx = L % gridDim.x;
    const int r = L / gridDim.x;
    by = r % gridDim.y; bz = r / gridDim.y;
  }
  const int m0 = by * BM, n0 = bx * BN;
  const long zA = (long)bz * batchA;
  const long zB = (long)bz * batchB;
  const long zC = (long)bz * batchC;

  const bf16* gp[CALLS];
#pragma unroll
  for (int q = 0; q < CALLS; ++q) {
    const int o = q * SPAN + t * 16;
    const bf16* base; long rbase; int local;
    if (o < NP * ABYTES) {
      const int p = o / ABYTES; local = o % ABYTES;
      base = (p == 0) ? Ah : (p == 1) ? Am : Al;
      rbase = zA + (long)m0 * K;
    } else {
      const int o2 = o - NP * ABYTES;
      const int p = o2 / BBYTES; local = o2 % BBYTES;
      base = (p == 0) ? Bh : (p == 1) ? Bm : Bl;
      rbase = zB + (long)n0 * K;
    }
    const int s = local >> 7;
    const int pc = (local >> 4) & 7;
    const int lc = pc ^ (s & 7);
    const int row = 2 * s + (lc >> 2);
    const int ke = (lc & 3) << 3;
    gp[q] = base + rbase + (long)row * K + ke;
  }
  const int lofs = wi * 1024;

  const int fr = ln & 15, cc = ln >> 4;
  const int c2 = ((fr & 1) << 2) | cc;
  int aoff[FI], boff[FJ];
#pragma unroll
  for (int i = 0; i < FI; ++i) {
    const int s = (wr * WM + i * 16 + fr) >> 1;
    aoff[i] = s * 128 + ((c2 ^ (s & 7)) << 4);
  }
#pragma unroll
  for (int j = 0; j < FJ; ++j) {
    const int s = (wc * WN + j * 16 + fr) >> 1;
    boff[j] = s * 128 + ((c2 ^ (s & 7)) << 4);
  }

  f32x4 acc1[FI][FJ] = {}, acc2[FI][FJ] = {};

  auto STAGE = [&](int buf, int kt) {
#pragma unroll
    for (int q = 0; q < CALLS; ++q)
      async16(smem + buf * HALF + q * SPAN + lofs, gp[q] + kt);
  };

  auto COMPUTE = [&](const char* rb) {
    bf16x8 AH[FI], BH[FJ], AX[FI], BX[FJ];
#pragma unroll
    for (int i = 0; i < FI; ++i) AH[i] = *(const bf16x8*)(rb + aoff[i]);
#pragma unroll
    for (int j = 0; j < FJ; ++j) BH[j] = *(const bf16x8*)(rb + NP * ABYTES + boff[j]);
#pragma unroll
    for (int i = 0; i < FI; ++i)
#pragma unroll
      for (int j = 0; j < FJ; ++j)
        acc1[i][j] = __builtin_amdgcn_mfma_f32_16x16x32_bf16(AH[i], BH[j], acc1[i][j], 0, 0, 0);
    if constexpr (NPROD == 6) {
#pragma unroll
      for (int i = 0; i < FI; ++i) AX[i] = *(const bf16x8*)(rb + 2 * ABYTES + aoff[i]);
#pragma unroll
      for (int j = 0; j < FJ; ++j) BX[j] = *(const bf16x8*)(rb + NP * ABYTES + 2 * BBYTES + boff[j]);
#pragma unroll
      for (int i = 0; i < FI; ++i)
#pragma unroll
        for (int j = 0; j < FJ; ++j) {
          acc2[i][j] = __builtin_amdgcn_mfma_f32_16x16x32_bf16(AH[i], BX[j], acc2[i][j], 0, 0, 0);
          acc2[i][j] = __builtin_amdgcn_mfma_f32_16x16x32_bf16(AX[i], BH[j], acc2[i][j], 0, 0, 0);
        }
    }
    if constexpr (NPROD >= 3) {
#pragma unroll
      for (int i = 0; i < FI; ++i) AX[i] = *(const bf16x8*)(rb + 1 * ABYTES + aoff[i]);
#pragma unroll
      for (int j = 0; j < FJ; ++j) BX[j] = *(const bf16x8*)(rb + NP * ABYTES + 1 * BBYTES + boff[j]);
#pragma unroll
      for (int i = 0; i < FI; ++i)
#pragma unroll
        for (int j = 0; j < FJ; ++j) {
          acc2[i][j] = __builtin_amdgcn_mfma_f32_16x16x32_bf16(AH[i], BX[j], acc2[i][j], 0, 0, 0);
          acc2[i][j] = __builtin_amdgcn_mfma_f32_16x16x32_bf16(AX[i], BH[j], acc2[i][j], 0, 0, 0);
          if constexpr (NPROD == 6)
            acc2[i][j] = __builtin_amdgcn_mfma_f32_16x16x32_bf16(AX[i], BX[j], acc2[i][j], 0, 0, 0);
        }
    }
  };

  STAGE(0, 0);
  int cur = 0;
  for (int kt = 32; kt < K; kt += 32) {
    STAGE(cur ^ 1, kt);
    wait_vm<CALLS>();
    __builtin_amdgcn_s_barrier();
    COMPUTE(smem + cur * HALF);
    asm volatile("s_waitcnt lgkmcnt(0)" ::: "memory");
    __builtin_amdgcn_s_barrier();
    cur ^= 1;
  }
  wait_vm<0>();
  __builtin_amdgcn_s_barrier();
  COMPUTE(smem + cur * HALF);

  const int fc = ln & 15;
  const int fr4 = (ln >> 4) << 2;
#pragma unroll
  for (int i = 0; i < FI; ++i) {
    const int rbase = m0 + wr * WM + i * 16 + fr4;
#pragma unroll
    for (int j = 0; j < FJ; ++j) {
      const int c = n0 + wc * WN + j * 16 + fc;
      const float bv = bias ? bias[c] : 0.0f;
#pragma unroll
      for (int q = 0; q < 4; ++q) {
        const float val = (acc1[i][j][q] + acc2[i][j][q]) * scale + bv;
        const long off = zC + (long)(rbase + q) * N + c;
        if constexpr (OUTMODE == 0) {
          C[off] = val;
        } else if constexpr (OUTMODE == 1) {
          const bf16 h = __float2bfloat16(val);
          const float r = val - __bfloat162float(h);
          const bf16 m = __float2bfloat16(r);
          Ch[off] = h; Cm[off] = m;
          Cl[off] = __float2bfloat16(r - __bfloat162float(m));
        } else if constexpr (OUTMODE == 2) {
          const bf16 h = __float2bfloat16(val);
          Ch[off] = h;
          Cm[off] = __float2bfloat16(val - __bfloat162float(h));
        } else {
          Ch[off] = __float2bfloat16(val);
        }
      }
    }
  }
}

// ---------- radix-select top-65 + fp64 boundary refine + softmax + attn ----------
__device__ __forceinline__ unsigned f2key(float f) {
  const unsigned u = __float_as_uint(f);
  return (u & 0x80000000u) ? ~u : (u | 0x80000000u);
}
__device__ __forceinline__ bool worse(float av, int ac, float bv, int bc) {
  return (av < bv) || (av == bv && ac > bc);
}

__global__ __launch_bounds__(256) void topk_kernel(
    const float* __restrict__ scores,
    const bf16* __restrict__ Qh, const bf16* __restrict__ Qm, const bf16* __restrict__ Ql,
    const bf16* __restrict__ Kh, const bf16* __restrict__ Km, const bf16* __restrict__ Kl,
    float* __restrict__ attn, bf16* __restrict__ attnh) {
  const int row = blockIdx.x;  // 0..8191
  const int t = threadIdx.x, ln = t & 63, w = t >> 6;
  const float* srow = scores + (long)row * kS;

  __shared__ __align__(16) unsigned hist[2048];
  __shared__ float s_wval[kSel];
  __shared__ int s_wcol[kSel];
  __shared__ float s_kv[kTopK];
  __shared__ int s_kc[kTopK];
  __shared__ unsigned wsum[4];
  __shared__ int s_cut, s_ngt, s_nw, s_ntie;
  __shared__ int s_tie[128];
  __shared__ float s_tieval;
  __shared__ int s_c0, s_c1, s_excl, s_slot;
  __shared__ float s_gap;
  __shared__ double rd0[4], rd1[4];

  if (t == 0) { s_nw = 0; s_ntie = 0; }

  float val[8]; unsigned key[8];
  {
    const float4 q0 = ((const float4*)srow)[t];
    const float4 q1 = ((const float4*)srow)[t + 256];
    val[0] = q0.x; val[1] = q0.y; val[2] = q0.z; val[3] = q0.w;
    val[4] = q1.x; val[5] = q1.y; val[6] = q1.z; val[7] = q1.w;
  }
#pragma unroll
  for (int j = 0; j < 8; ++j) key[j] = f2key(val[j]);

  unsigned alive = 0xFFu, winner = 0u;
  int rem = kSel, done = 0;

  for (int level = 0; level < 3; ++level) {
    const int shift = (level == 0) ? 21 : (level == 1) ? 10 : 0;
    const unsigned bmask = (level == 2) ? 0x3FFu : 0x7FFu;
    for (int i = t; i < 2048; i += 256) hist[i] = 0u;
    __syncthreads();
#pragma unroll
    for (int j = 0; j < 8; ++j)
      if (alive & (1u << j)) atomicAdd(&hist[(key[j] >> shift) & bmask], 1u);
    __syncthreads();

    unsigned h[8]; unsigned ts = 0u;
#pragma unroll
    for (int b = 0; b < 8; ++b) { h[b] = hist[8 * t + b]; ts += h[b]; }
    unsigned ss = ts;
#pragma unroll
    for (int off = 1; off < 64; off <<= 1) {
      const unsigned o = __shfl_down(ss, off);
      if (ln + off < 64) ss += o;
    }
    if (ln == 0) wsum[w] = ss;
    __syncthreads();
    unsigned run = ss - ts;
    for (int u = w + 1; u < 4; ++u) run += wsum[u];
#pragma unroll
    for (int b = 7; b >= 0; --b) {
      if (run < (unsigned)rem && run + h[b] >= (unsigned)rem) {
        s_cut = 8 * t + b;
        s_ngt = (int)run;
      }
      run += h[b];
    }
    __syncthreads();
    const int cut = s_cut;
    const int ngt = s_ngt;
    const int incut = (int)hist[cut];
    rem -= ngt;
#pragma unroll
    for (int j = 0; j < 8; ++j) {
      if (!(alive & (1u << j))) continue;
      const int b = (int)((key[j] >> shift) & bmask);
      if (b > cut) { winner |= 1u << j; alive &= ~(1u << j); }
      else if (b < cut) alive &= ~(1u << j);
    }
    if (incut == rem) {
      winner |= alive; alive = 0u; done = 1;
    } else if (level == 2) {
#pragma unroll
      for (int j = 0; j < 8; ++j)
        if (alive & (1u << j)) {
          const int pos = atomicAdd(&s_ntie, 1);
          const int col = (j < 4) ? (4 * t + j) : (1024 + 4 * t + j - 4);
          if (pos < 128) s_tie[pos] = col;
          s_tieval = val[j];
        }
      __syncthreads();
      if (w == 0) {
        volatile int* vt = s_tie;
        const int n = (s_ntie < 128) ? s_ntie : 128;
        const int take = (rem < n) ? rem : n;
        for (int it = 0; it < take; ++it) {
          int c0 = (ln < n) ? vt[ln] : 0x7FFFFFFF;
          int c1 = (ln + 64 < n) ? vt[ln + 64] : 0x7FFFFFFF;
          int bc, bs;
          if (c1 < c0) { bc = c1; bs = ln + 64; } else { bc = c0; bs = ln; }
#pragma unroll
          for (int off = 32; off; off >>= 1) {
            const int oc = __shfl_xor(bc, off);
            const int os = __shfl_xor(bs, off);
            if (oc < bc) { bc = oc; bs = os; }
          }
          if (ln == 0) {
            vt[bs] = 0x7FFFFFFF;
            const int p = s_nw;
            s_wcol[p] = bc; s_wval[p] = s_tieval;
            s_nw = p + 1;
          }
        }
      }
      alive = 0u;
      done = 1;
    }
    __syncthreads();
    if (done) break;
  }

#pragma unroll
  for (int j = 0; j < 8; ++j)
    if (winner & (1u << j)) {
      const int pos = atomicAdd(&s_nw, 1);
      const int col = (j < 4) ? (4 * t + j) : (1024 + 4 * t + j - 4);
      if (pos < kSel) { s_wcol[pos] = col; s_wval[pos] = val[j]; }
    }
  __syncthreads();

  // ---- find worst & second-worst among the 65 (wave 0) ----
  if (w == 0) {
    float wv = s_wval[ln]; int wc2 = s_wcol[ln];
    float sv = 1e30f; int sc = -1;
    if (ln == 0) {
      const float v64 = s_wval[64]; const int c64 = s_wcol[64];
      if (worse(v64, c64, wv, wc2)) { sv = wv; sc = wc2; wv = v64; wc2 = c64; }
      else { sv = v64; sc = c64; }
    }
#pragma unroll
    for (int off = 32; off; off >>= 1) {
      const float owv = __shfl_down(wv, off); const int owc = __shfl_down(wc2, off);
      const float osv = __shfl_down(sv, off); const int osc = __shfl_down(sc, off);
      if (worse(owv, owc, wv, wc2)) {
        const bool x = worse(wv, wc2, osv, osc);
        sv = x ? wv : osv; sc = x ? wc2 : osc;
        wv = owv; wc2 = owc;
      } else {
        const bool x = worse(owv, owc, sv, sc);
        sv = x ? owv : sv; sc = x ? owc : sc;
      }
    }
    if (ln == 0) {
      s_c0 = wc2; s_c1 = sc; s_gap = sv - wv;
      s_excl = wc2;
    }
  }
  __syncthreads();

  // ---- fp64 boundary refine when the 64/65 approx gap is ambiguous ----
  if (s_nw == kSel && s_gap < 3e-4f) {
    const int b = row >> 11;
    const int cw = s_c0, cs = s_c1;
    const long qoff = (long)row * kD;
    const long k0off = ((long)(b << 11) + cw) * kD;
    const long k1off = ((long)(b << 11) + cs) * kD;
    double p0 = 0.0, p1 = 0.0;
    const unsigned qhp = ((const unsigned*)(Qh + qoff))[t];
    const unsigned qmp = ((const unsigned*)(Qm + qoff))[t];
    const unsigned qlp = ((const unsigned*)(Ql + qoff))[t];
    const unsigned k0h = ((const unsigned*)(Kh + k0off))[t];
    const unsigned k0m = ((const unsigned*)(Km + k0off))[t];
    const unsigned k0l = ((const unsigned*)(Kl + k0off))[t];
    const unsigned k1h = ((const unsigned*)(Kh + k1off))[t];
    const unsigned k1m = ((const unsigned*)(Km + k1off))[t];
    const unsigned k1l = ((const unsigned*)(Kl + k1off))[t];
    auto bflo = [](unsigned u) { return __uint_as_float(u << 16); };
    auto bfhi = [](unsigned u) { return __uint_as_float(u & 0xFFFF0000u); };
    {
      const double q0 = (double)bflo(qhp) + (double)bflo(qmp) + (double)bflo(qlp);
      const double q1 = (double)bfhi(qhp) + (double)bfhi(qmp) + (double)bfhi(qlp);
      const double a0 = (double)bflo(k0h) + (double)bflo(k0m) + (double)bflo(k0l);
      const double a1 = (double)bfhi(k0h) + (double)bfhi(k0m) + (double)bfhi(k0l);
      const double b0 = (double)bflo(k1h) + (double)bflo(k1m) + (double)bflo(k1l);
      const double b1 = (double)bfhi(k1h) + (double)bfhi(k1m) + (double)bfhi(k1l);
      p0 = q0 * a0 + q1 * a1;
      p1 = q0 * b0 + q1 * b1;
    }
#pragma unroll
    for (int off = 32; off; off >>= 1) {
      p0 += __shfl_down(p0, off);
      p1 += __shfl_down(p1, off);
    }
    if (ln == 0) { rd0[w] = p0; rd1[w] = p1; }
    __syncthreads();
    if (t == 0) {
      const double e0 = rd0[0] + rd0[1] + rd0[2] + rd0[3];
      const double e1 = rd1[0] + rd1[1] + rd1[2] + rd1[3];
      if (e0 > e1 || (e0 == e1 && cw < cs)) s_excl = cs; else s_excl = cw;
    }
    __syncthreads();
  }

  // compact to 64 kept entries
  if (t == 0) s_slot = kSel - 1;
  __syncthreads();
  if (t < kSel && s_wcol[t] == s_excl) s_slot = t;
  __syncthreads();
  if (t < kTopK) {
    const int src = t + (t >= s_slot ? 1 : 0);
    s_kc[t] = s_wcol[src];
    s_kv[t] = s_wval[src];
  }
  __syncthreads();

  // softmax over kept 64 (wave 0)
  if (w == 0) {
    const float v = s_kv[ln];
    float m = v;
#pragma unroll
    for (int off = 32; off; off >>= 1) m = fmaxf(m, __shfl_xor(m, off));
    float p = expf(v - m);
    float Z = p;
#pragma unroll
    for (int off = 32; off; off >>= 1) Z += __shfl_xor(Z, off);
    p /= Z;
    s_kv[ln] = p;
  }
  __syncthreads();

  // dense attn row: fp32 to d_out + bf16 copy for the out-GEMM
  float* lrow = (float*)hist;
  ((float4*)lrow)[t] = make_float4(0.f, 0.f, 0.f, 0.f);
  ((float4*)lrow)[t + 256] = make_float4(0.f, 0.f, 0.f, 0.f);
  __syncthreads();
  if (t < kTopK) lrow[s_kc[t]] = s_kv[t];
  __syncthreads();
  float4* dst = (float4*)(attn + (long)row * kS);
  dst[t] = ((const float4*)lrow)[t];
  dst[t + 256] = ((const float4*)lrow)[t + 256];
  {
    ushort4 hv;
    const float* src = lrow + t * 8;
    unsigned short u[8];
#pragma unroll
    for (int j = 0; j < 8; ++j)
      u[j] = __builtin_bit_cast(unsigned short, __float2bfloat16(src[j]));
    hv.x = u[0] | 0; hv.y = u[2] | 0; hv.z = u[4] | 0; hv.w = u[6] | 0;
    // pack 8 bf16 as 4 x u32 (lo|hi<<16) via two ushort4 stores -> one uint4
    unsigned p0 = (unsigned)u[0] | ((unsigned)u[1] << 16);
    unsigned p1 = (unsigned)u[2] | ((unsigned)u[3] << 16);
    unsigned p2 = (unsigned)u[4] | ((unsigned)u[5] << 16);
    unsigned p3 = (unsigned)u[6] | ((unsigned)u[7] << 16);
    ((uint4*)(attnh + (long)row * kS))[t] = make_uint4(p0, p1, p2, p3);
  }
}

extern "C" void kernel_launch(void* const* d_in, const int* in_sizes, int n_in,
                              void* d_out, int out_size, void* d_ws, size_t ws_size,
                              hipStream_t stream) {
  (void)in_sizes; (void)n_in; (void)out_size; (void)ws_size;
  const float* x = (const float*)d_in[0];
  const float* Wq = (const float*)d_in[1];
  const float* bq = (const float*)d_in[2];
  const float* Wk = (const float*)d_in[3];
  const float* bk = (const float*)d_in[4];
  const float* Wv = (const float*)d_in[5];
  const float* bv = (const float*)d_in[6];
  const float* Wo = (const float*)d_in[7];
  const float* bo = (const float*)d_in[8];

  float* out = (float*)d_out;             // [4,2048,512]
  float* attn = out + (long)kRows * kD;   // [4,2048,2048]

  const size_t SZ_ROWS = (size_t)kRows * kD * 2;    // 8 MB bf16 [8192,512]
  const size_t SZ_W = (size_t)kD * kD * 2;          // 512 KB bf16 [512,512]
  const size_t SZ_ATTNH = (size_t)kRows * kS * 2;   // 33.5 MB bf16 [8192,2048]
  char* ws = (char*)d_ws;

  // region A (67.1 MB): x3 splits first, then scores overwrites (x3 dead by then)
  bf16* xh = (bf16*)(ws + 0);
  bf16* xm = (bf16*)(ws + SZ_ROWS);
  bf16* xl = (bf16*)(ws + 2 * SZ_ROWS);
  float* scores = (float*)(ws + 0);  // 67108864 B
  size_t off = 67108864;
  auto alloc = [&](size_t bytes) {
    void* p = ws + off;
    off += (bytes + 255) & ~(size_t)255;
    return p;
  };
  bf16* Wqh = (bf16*)alloc(SZ_W); bf16* Wqm = (bf16*)alloc(SZ_W); bf16* Wql = (bf16*)alloc(SZ_W);
  bf16* Wkh = (bf16*)alloc(SZ_W); bf16* Wkm = (bf16*)alloc(SZ_W); bf16* Wkl = (bf16*)alloc(SZ_W);
  bf16* Wvh = (bf16*)alloc(SZ_W); bf16* Wvm = (bf16*)alloc(SZ_W);
  bf16* Woh = (bf16*)alloc(SZ_W); bf16* Wom = (bf16*)alloc(SZ_W);
  bf16* Wvl = (bf16*)alloc(SZ_W); bf16* Wol = (bf16*)alloc(SZ_W);
  // region C (48 MB): Q3,K3 splits (live through topk for the refine)
  char* regC = (char*)alloc(6 * SZ_ROWS);
  bf16* Qh = (bf16*)(regC);
  bf16* Qm = (bf16*)(regC + SZ_ROWS);
  bf16* Ql = (bf16*)(regC + 2 * SZ_ROWS);
  bf16* Kh = (bf16*)(regC + 3 * SZ_ROWS);
  bf16* Km = (bf16*)(regC + 4 * SZ_ROWS);
  bf16* Kl = (bf16*)(regC + 5 * SZ_ROWS);
  // VWT bf16 [4][512][2048] (8.4 MB), persistent to the final GEMM
  bf16* VWTh = (bf16*)alloc((size_t)kBatch * kD * kS * 2);
  // V h/m (16 MB), dead after the VWT GEMM -> attn_h aliases from Vh
  bf16* Vh = (bf16*)alloc(SZ_ROWS);
  bf16* Vm = (bf16*)alloc(SZ_ROWS);
  alloc(SZ_ATTNH - 2 * SZ_ROWS);   // extend region so attnh fits
  bf16* attnh = Vh;                // alias: V dead before topk writes attnh

  const float inv_sqrt_d = 1.0f / sqrtf((float)kD);

  // 1. splits
  split3<<<2048, 256, 0, stream>>>(x, xh, xm, xl, kRows * kD);
  {
    WSplitArgs a;
    a.w[0] = Wq; a.w[1] = Wk; a.w[2] = Wv; a.w[3] = Wo;
    a.h[0] = Wqh; a.h[1] = Wkh; a.h[2] = Wvh; a.h[3] = Woh;
    a.m[0] = Wqm; a.m[1] = Wkm; a.m[2] = Wvm; a.m[3] = Wom;
    a.l[0] = Wql; a.l[1] = Wkl; a.l[2] = Wvl; a.l[3] = Wol;
    split3x4<<<dim3(128, 4), 256, 0, stream>>>(a, kD * kD);
  }

  const int LDS_P6 = 2 * 3 * (128 + 64) * 64;   // 73728
  const int LDS_P3 = 2 * 2 * (128 + 64) * 64;   // 49152
  const int LDS_S3 = 2 * 2 * (256 + 128) * 64;  // 98304 (scores, 3-product)
  const int LDS_O1 = 2 * 1 * (128 + 64) * 64;   // 24576 (out GEMM, 1-product)
  const dim3 gP(kD / 64, kRows / 128, 1);         // 512 blocks
  const dim3 gScore(kS / 128, kS / 256, kBatch);  // 512 blocks
  const dim3 gVWT(kS / 64, kD / 128, kBatch);     // (32, 4, 4) = 512 blocks
  const dim3 gOut(kD / 64, kS / 128, kBatch);     // (8, 16, 4) = 512 blocks

  // 2. Q,K projections (6-product) -> h/m/l (l feeds the fp64 refine)
  gemm_pipe<1, 6, 128, 64, 2, 2><<<gP, 256, LDS_P6, stream>>>(xh, xm, xl, Wqh, Wqm, Wql,
      nullptr, Qh, Qm, Ql, bq, 1.0f, kD, kD, 0, 0, 0);
  gemm_pipe<1, 6, 128, 64, 2, 2><<<gP, 256, LDS_P6, stream>>>(xh, xm, xl, Wkh, Wkm, Wkl,
      nullptr, Kh, Km, Kl, bk, 1.0f, kD, kD, 0, 0, 0);
  // 3. V projection (3-product) -> h/m splits (includes bv)
  gemm_pipe<2, 3, 128, 64, 2, 2><<<gP, 256, LDS_P3, stream>>>(xh, xm, nullptr, Wvh, Wvm, nullptr,
      nullptr, Vh, Vm, nullptr, bv, 1.0f, kD, kD, 0, 0, 0);
  // 4. VWT[b][e][c] = sum_d Wo[e][d] V[b][c][d]  (3-product) -> bf16 h
  gemm_pipe<3, 3, 128, 64, 2, 2><<<gVWT, 256, LDS_P3, stream>>>(Woh, Wom, nullptr, Vh, Vm, nullptr,
      nullptr, VWTh, nullptr, nullptr, nullptr, 1.0f, kS, kD,
      0, (long)kS * kD, (long)kD * kS);
  // 5. scores = (Q @ K^T) * inv_sqrt_d — 3-product approx (boundary refined later)
  gemm_pipe<0, 3, 256, 128, 4, 2><<<gScore, 512, LDS_S3, stream>>>(Qh, Qm, nullptr, Kh, Km, nullptr,
      scores, nullptr, nullptr, nullptr, nullptr, inv_sqrt_d, kS, kD,
      (long)kS * kD, (long)kS * kD, (long)kS * kS);
  // 6. top-65 select + fp64 boundary refine + softmax + attn fp32 + attn bf16
  topk_kernel<<<kRows, 256, 0, stream>>>(scores, Qh, Qm, Ql, Kh, Km, Kl, attn, attnh);
  // 7. out = attn_bf16 @ VWT^T + bo  (1-product dense GEMM; replaces the gather)
  gemm_pipe<0, 1, 128, 64, 2, 2><<<gOut, 256, LDS_O1, stream>>>(attnh, nullptr, nullptr,
      VWTh, nullptr, nullptr, out, nullptr, nullptr, nullptr, bo, 1.0f, kD, kS,
      (long)kS * kS, (long)kD * kS, (long)kS * kD);
}